// Round 2
// baseline (3847.103 us; speedup 1.0000x reference)
//
#include <hip/hip_runtime.h>
#include <stdint.h>

// B=16, H=180, W=240, N=8M events of 5 floats (x,y,t,p,b), b sorted.
constexpr int NB   = 16;
constexpr int NH   = 180;
constexpr int NW   = 240;
constexpr int FULL = NB * NH * NW;         // 691200
constexpr int SEG  = (NH / 2) * (NW / 2);  // 10800
constexpr int HALF = NB * SEG;             // 172800
constexpr int NBLK = 256;                  // event-pass blocks (1/CU)
constexpr int EVT  = 512;                  // threads per event-pass block

// ---- ws layout (4-byte words) ----
// accumulators for rare slow-path events (batch-boundary "foreign", bleed):
constexpr int O_TMAX  = 0;                  // u32[16] float-bits, atomicMax
constexpr int O_CONT  = 16;                 // u32[FULL]
constexpr int O_CNT   = O_CONT + FULL;      // u32[HALF]
constexpr int O_TSUM  = O_CNT + HALF;       // f32[HALF]
constexpr int O_BLEED = O_TSUM + HALF;      // f32[HALF]
constexpr int ZERO_WORDS = O_BLEED + HALF;  // everything above must be zeroed
// private-histogram scratch (fully overwritten each call, no zeroing):
constexpr int O_BMAP  = ZERO_WORDS;             // i32[NBLK] block->batch
constexpr int O_HIST  = O_BMAP + NBLK;          // u8[NBLK][43200] full-res counts
constexpr int O_CNTP  = O_HIST + NBLK * 10800;  // u8[NBLK][10800] half-res counts
constexpr int O_TSP   = O_CNTP + NBLK * 2700;   // f32[NBLK][10800] half-res t-sums
constexpr int WS_WORDS_FAST = O_TSP + NBLK * 10800;   // ~29.7 MB

__global__ __launch_bounds__(256) void k_init(unsigned int* __restrict__ ws) {
    int i = blockIdx.x * blockDim.x + threadIdx.x;
    int stride = gridDim.x * blockDim.x;
    for (; i < ZERO_WORDS; i += stride) ws[i] = 0u;
}

// ---------------- fast path: LDS-privatized histograms ----------------

// Pass 1: full-res histogram (u8-packed in LDS) + per-batch tmax.
__global__ __launch_bounds__(EVT) void k_hist(const float* __restrict__ ev, int n,
                                              unsigned int* __restrict__ ws) {
    unsigned int* tmaxb    = ws + O_TMAX;
    unsigned int* cont_acc = ws + O_CONT;
    int*          bmap     = (int*)(ws + O_BMAP);
    unsigned int* histp    = ws + O_HIST;   // u8[43200] per block, word view

    __shared__ unsigned int h[10800];       // 43200 u8 cells packed
    __shared__ float sm[EVT / 64];
    int tid = threadIdx.x;
    for (int i = tid; i < 10800; i += EVT) h[i] = 0u;

    int chunk = (n + NBLK - 1) / NBLK;
    int start = blockIdx.x * chunk;
    int end   = min(start + chunk, n);
    int bi0   = (start < n) ? (int)ev[(size_t)5 * start + 4] : -1;
    if (tid == 0) bmap[blockIdx.x] = bi0;
    __syncthreads();

    float tloc = 0.0f;  // t >= 0
    for (int i = start + tid; i < end; i += EVT) {
        const float* r = ev + (size_t)5 * i;
        int xi = (int)r[0], yi = (int)r[1];
        float t = r[2];
        int bi = (int)r[4];
        if (bi == bi0) {
            tloc = fmaxf(tloc, t);
            int cell = xi + NW * yi;
            atomicAdd(&h[cell >> 2], 1u << ((cell & 3) * 8));
        } else {  // rare: batch boundary inside chunk
            atomicMax(&tmaxb[bi], __float_as_uint(t));
            atomicAdd(&cont_acc[xi + NW * yi + NH * NW * bi], 1u);
        }
    }
    __syncthreads();

    unsigned int* dst = histp + (size_t)blockIdx.x * 10800;
    for (int i = tid; i < 10800; i += EVT) dst[i] = h[i];

    // block tmax reduce -> one global atomicMax
#pragma unroll
    for (int o = 32; o > 0; o >>= 1) tloc = fmaxf(tloc, __shfl_xor(tloc, o));
    if ((tid & 63) == 0) sm[tid >> 6] = tloc;
    __syncthreads();
    if (tid == 0 && bi0 >= 0) {
        float m = sm[0];
        for (int w = 1; w < EVT / 64; ++w) m = fmaxf(m, sm[w]);
        atomicMax(&tmaxb[bi0], __float_as_uint(m));
    }
}

// Pass 2: half-res count (u8-packed) + raw-t sums (f32) in LDS.
// idx_k = x//2 + 60*y + 10800*b exactly; loc = x//2 + 60*y can reach 10859
// (bleed into next batch's segment) -> slow path, matches jax mode="drop".
__global__ __launch_bounds__(EVT) void k_vox(const float* __restrict__ ev, int n,
                                             unsigned int* __restrict__ ws) {
    unsigned int* cnt_acc  = ws + O_CNT;
    float*        tsum_acc = (float*)(ws + O_TSUM);
    float*        bleed    = (float*)(ws + O_BLEED);
    unsigned int* cntp     = ws + O_CNTP;
    float*        tsp      = (float*)(ws + O_TSP);

    __shared__ unsigned int c8[2700];   // 10800 u8 counts packed
    __shared__ float ts[10800];
    int tid = threadIdx.x;
    for (int i = tid; i < 2700; i += EVT) c8[i] = 0u;
    for (int i = tid; i < 10800; i += EVT) ts[i] = 0.0f;

    int chunk = (n + NBLK - 1) / NBLK;
    int start = blockIdx.x * chunk;
    int end   = min(start + chunk, n);
    int bi0   = (start < n) ? (int)ev[(size_t)5 * start + 4] : -1;
    __syncthreads();

    for (int i = start + tid; i < end; i += EVT) {
        const float* r = ev + (size_t)5 * i;
        int xi = (int)r[0], yi = (int)r[1];
        float t = r[2];
        int bi = (int)r[4];
        int loc = (xi >> 1) + (NW / 4) * yi;
        if (bi == bi0 && loc < SEG) {
            atomicAdd(&c8[loc >> 2], 1u << ((loc & 3) * 8));
            atomicAdd(&ts[loc], t);
        } else {  // rare: foreign batch or bleed
            int ik = loc + SEG * bi;
            if (ik < HALF) {
                atomicAdd(&cnt_acc[ik], 1u);
                if (loc >= SEG) atomicAdd(&bleed[ik], t);  // batch bi's t in segment bi+1
                else            atomicAdd(&tsum_acc[ik], t);
            }
        }
    }
    __syncthreads();

    unsigned int* dc = cntp + (size_t)blockIdx.x * 2700;
    for (int i = tid; i < 2700; i += EVT) dc[i] = c8[i];
    float* dt = tsp + (size_t)blockIdx.x * 10800;
    for (int i = tid; i < 10800; i += EVT) dt[i] = ts[i];
}

// Merge private histograms + slow-path accumulators; emit all 5 outputs.
__global__ __launch_bounds__(256) void k_reduce(const unsigned int* __restrict__ ws,
                                                float* __restrict__ out) {
    const unsigned int* tmaxb    = ws + O_TMAX;
    const unsigned int* cont_acc = ws + O_CONT;
    const unsigned int* cnt_acc  = ws + O_CNT;
    const float*        tsum_acc = (const float*)(ws + O_TSUM);
    const float*        bleedp   = (const float*)(ws + O_BLEED);
    const int*          bmap     = (const int*)(ws + O_BMAP);
    const uint8_t*      histp    = (const uint8_t*)(ws + O_HIST);
    const uint8_t*      cntp     = (const uint8_t*)(ws + O_CNTP);
    const float*        tsp      = (const float*)(ws + O_TSP);

    __shared__ int sbmap[NBLK];
    int tid = threadIdx.x;
    sbmap[tid] = bmap[tid];
    __syncthreads();

    int v = blockIdx.x * 256 + tid;      // grid sized exactly HALF/256
    int b   = v / SEG;
    int rem = v - b * SEG;
    int i   = rem / (NW / 2);
    int j   = rem - i * (NW / 2);
    int cbl = (2 * i) * NW + 2 * j;      // local full-res base of the 2x2 block
    int cbg = b * (NH * NW) + cbl;

    unsigned c00 = cont_acc[cbg],      c01 = cont_acc[cbg + 1];
    unsigned c10 = cont_acc[cbg + NW], c11 = cont_acc[cbg + NW + 1];
    unsigned cnt = cnt_acc[v];
    float tsum = tsum_acc[v];
    float bl   = bleedp[v];

    for (int blk = 0; blk < NBLK; ++blk) {
        if (sbmap[blk] == b) {
            const uint8_t* hp = histp + (size_t)blk * 43200 + cbl;
            uint16_t r0 = *(const uint16_t*)hp;
            uint16_t r1 = *(const uint16_t*)(hp + NW);
            c00 += r0 & 0xff; c01 += r0 >> 8;
            c10 += r1 & 0xff; c11 += r1 >> 8;
            cnt  += cntp[(size_t)blk * 10800 + rem];
            tsum += tsp[(size_t)blk * 10800 + rem];
        }
    }

    float* out_cont = out;
    float* out_cnt  = out + FULL;
    float* out_tim  = out + FULL + HALF;
    float* out_dx   = out + FULL + 2 * HALF;
    float* out_dy   = out + FULL + 3 * HALF;

    out_cont[cbg]          = (float)c00;
    out_cont[cbg + 1]      = (float)c01;
    out_cont[cbg + NW]     = (float)c10;
    out_cont[cbg + NW + 1] = (float)c11;
    out_cnt[v] = (float)cnt;

    float tm  = __uint_as_float(tmaxb[b]);
    float tmp = (b > 0) ? __uint_as_float(tmaxb[b - 1]) : 1.0f;  // bleed==0 at b==0
    float s   = tsum / tm + bl / tmp;
    out_tim[v] = s / (float)(cnt == 0 ? 1u : cnt);

    out_dx[v] = (float)((int)c00 - (int)c01 + (int)c10 - (int)c11);
    out_dy[v] = (float)((int)c00 + (int)c01 - (int)c10 - (int)c11);
}

// ---------------- fallback path (R1 global-atomic version) ----------------

__global__ __launch_bounds__(256) void f_events(const float* __restrict__ ev, int n,
                                                unsigned int* __restrict__ ws) {
    unsigned int* tmaxb = ws + O_TMAX;
    int*   cont  = (int*)(ws + O_CONT);
    int*   cnt   = (int*)(ws + O_CNT);
    float* tsum  = (float*)(ws + O_TSUM);
    float* bleed = (float*)(ws + O_BLEED);
    __shared__ unsigned int smax[NB];
    if (threadIdx.x < NB) smax[threadIdx.x] = 0u;
    __syncthreads();
    int chunk = (n + gridDim.x - 1) / (int)gridDim.x;
    int start = blockIdx.x * chunk;
    int end   = min(start + chunk, n);
    for (int i = start + (int)threadIdx.x; i < end; i += (int)blockDim.x) {
        const float* r = ev + (size_t)5 * (size_t)i;
        int xi = (int)r[0], yi = (int)r[1], bi = (int)r[4];
        float t = r[2];
        atomicMax(&smax[bi], __float_as_uint(t));
        atomicAdd(&cont[xi + NW * yi + NW * NH * bi], 1);
        int loc = (xi >> 1) + (NW / 4) * yi;
        int ik  = loc + SEG * bi;
        if (ik < HALF) {
            atomicAdd(&cnt[ik], 1);
            if (loc >= SEG) atomicAdd(&bleed[ik], t);
            else            atomicAdd(&tsum[ik], t);
        }
    }
    __syncthreads();
    if (threadIdx.x < NB) {
        unsigned v = smax[threadIdx.x];
        if (v) atomicMax(&tmaxb[threadIdx.x], v);
    }
}

__global__ __launch_bounds__(256) void f_epilogue(const unsigned int* __restrict__ ws,
                                                  float* __restrict__ out) {
    const unsigned int* tmaxb = ws + O_TMAX;
    const int*   cont  = (const int*)(ws + O_CONT);
    const int*   cnt   = (const int*)(ws + O_CNT);
    const float* tsum  = (const float*)(ws + O_TSUM);
    const float* bleed = (const float*)(ws + O_BLEED);
    int v = blockIdx.x * blockDim.x + threadIdx.x;
    if (v >= HALF) return;
    int b   = v / SEG;
    int rem = v - b * SEG;
    int i   = rem / (NW / 2);
    int j   = rem - i * (NW / 2);
    int cbase = b * (NH * NW) + (2 * i) * NW + 2 * j;
    int c00 = cont[cbase],      c01 = cont[cbase + 1];
    int c10 = cont[cbase + NW], c11 = cont[cbase + NW + 1];
    float* out_cont = out;
    out_cont[cbase]          = (float)c00;
    out_cont[cbase + 1]      = (float)c01;
    out_cont[cbase + NW]     = (float)c10;
    out_cont[cbase + NW + 1] = (float)c11;
    int c = cnt[v];
    out[FULL + v] = (float)c;
    float tm  = __uint_as_float(tmaxb[b]);
    float tmp = (b > 0) ? __uint_as_float(tmaxb[b - 1]) : 1.0f;
    float s   = tsum[v] / tm + bleed[v] / tmp;
    out[FULL + HALF + v] = s / (float)(c == 0 ? 1 : c);
    out[FULL + 2 * HALF + v] = (float)(c00 - c01 + c10 - c11);
    out[FULL + 3 * HALF + v] = (float)(c00 + c01 - c10 - c11);
}

extern "C" void kernel_launch(void* const* d_in, const int* in_sizes, int n_in,
                              void* d_out, int out_size, void* d_ws, size_t ws_size,
                              hipStream_t stream) {
    const float* ev = (const float*)d_in[0];
    int n = in_sizes[0] / 5;
    unsigned int* ws = (unsigned int*)d_ws;
    float* out = (float*)d_out;

    hipLaunchKernelGGL(k_init, dim3(512), dim3(256), 0, stream, ws);

    if (ws_size >= (size_t)WS_WORDS_FAST * 4u) {
        hipLaunchKernelGGL(k_hist, dim3(NBLK), dim3(EVT), 0, stream, ev, n, ws);
        hipLaunchKernelGGL(k_vox,  dim3(NBLK), dim3(EVT), 0, stream, ev, n, ws);
        hipLaunchKernelGGL(k_reduce, dim3(HALF / 256), dim3(256), 0, stream, ws, out);
    } else {
        hipLaunchKernelGGL(f_events, dim3(2048), dim3(256), 0, stream, ev, n, ws);
        hipLaunchKernelGGL(f_epilogue, dim3((HALF + 255) / 256), dim3(256), 0, stream, ws, out);
    }
}

// Round 3
// 432.403 us; speedup vs baseline: 8.8970x; 8.8970x over previous
//
#include <hip/hip_runtime.h>
#include <stdint.h>

// B=16, H=180, W=240, N=8M events of 5 floats (x,y,t,p,b), b sorted.
constexpr int NB   = 16;
constexpr int NH   = 180;
constexpr int NW   = 240;
constexpr int FULL = NB * NH * NW;         // 691200
constexpr int SEG  = (NH / 2) * (NW / 2);  // 10800
constexpr int HALF = NB * SEG;             // 172800
constexpr int NBLK = 256;                  // event-pass blocks (1/CU)
constexpr int EVT  = 1024;                 // threads per event-pass block (16 waves/CU)

// ---- ws layout (4-byte words) ----
// accumulators for rare slow-path events (batch-boundary "foreign", bleed):
constexpr int O_TMAX  = 0;                  // u32[16] float-bits, atomicMax
constexpr int O_CONT  = 16;                 // u32[FULL]
constexpr int O_CNT   = O_CONT + FULL;      // u32[HALF]
constexpr int O_TSUM  = O_CNT + HALF;       // f32[HALF]
constexpr int O_BLEED = O_TSUM + HALF;      // f32[HALF]
constexpr int ZERO_WORDS = O_BLEED + HALF;  // everything above must be zeroed
// private-histogram scratch (fully overwritten each call, no zeroing):
constexpr int O_BMAP  = ZERO_WORDS;             // i32[NBLK] block->batch
constexpr int O_HIST  = O_BMAP + NBLK;          // u8[NBLK][43200] full-res counts
constexpr int O_CNTP  = O_HIST + NBLK * 10800;  // u8[NBLK][10800] half-res counts
constexpr int O_TSP   = O_CNTP + NBLK * 2700;   // f32[NBLK][10800] half-res t-sums
constexpr int WS_WORDS_FAST = O_TSP + NBLK * 10800;   // ~29.7 MB

__global__ __launch_bounds__(256) void k_init(unsigned int* __restrict__ ws) {
    int i = blockIdx.x * blockDim.x + threadIdx.x;
    int stride = gridDim.x * blockDim.x;
    for (; i < ZERO_WORDS; i += stride) ws[i] = 0u;
}

// ---------------- fast path: LDS-privatized histograms ----------------

// Pass 1: full-res histogram (u8-packed in LDS) + per-batch tmax.
// tmax goes through LDS smax[16]; NEVER a per-event global atomic to a shared
// address (R2 lesson: 234K same-address global atomicMax serialized -> 3.5ms).
__global__ __launch_bounds__(EVT) void k_hist(const float* __restrict__ ev, int n,
                                              unsigned int* __restrict__ ws) {
    unsigned int* tmaxb    = ws + O_TMAX;
    unsigned int* cont_acc = ws + O_CONT;
    int*          bmap     = (int*)(ws + O_BMAP);
    unsigned int* histp    = ws + O_HIST;   // u8[43200] per block, word view

    __shared__ unsigned int h[10800];       // 43200 u8 cells packed
    __shared__ unsigned int smax[NB];
    int tid = threadIdx.x;
    for (int i = tid; i < 10800; i += EVT) h[i] = 0u;
    if (tid < NB) smax[tid] = 0u;

    int chunk = (n + NBLK - 1) / NBLK;
    int start = blockIdx.x * chunk;
    int end   = min(start + chunk, n);
    int bi0   = (start < n) ? (int)ev[(size_t)5 * start + 4] : -1;
    if (tid == 0) bmap[blockIdx.x] = bi0;
    __syncthreads();

    float tloc = 0.0f;  // t >= 0
    for (int i = start + tid; i < end; i += EVT) {
        const float* r = ev + (size_t)5 * i;
        int xi = (int)r[0], yi = (int)r[1];
        float t = r[2];
        int bi = (int)r[4];
        if (bi == bi0) {
            tloc = fmaxf(tloc, t);                       // free register chain
            int cell = xi + NW * yi;
            atomicAdd(&h[cell >> 2], 1u << ((cell & 3) * 8));
        } else {  // batch boundary inside chunk (~15 blocks, up to ~half chunk)
            atomicMax(&smax[bi], __float_as_uint(t));    // LDS, cheap
            atomicAdd(&cont_acc[xi + NW * yi + NH * NW * bi], 1u);
        }
    }

    // per-wave reduce of the fast-path tmax -> one LDS atomic per wave
#pragma unroll
    for (int o = 32; o > 0; o >>= 1) tloc = fmaxf(tloc, __shfl_xor(tloc, o));
    if ((tid & 63) == 0 && bi0 >= 0) atomicMax(&smax[bi0], __float_as_uint(tloc));
    __syncthreads();

    unsigned int* dst = histp + (size_t)blockIdx.x * 10800;
    for (int i = tid; i < 10800; i += EVT) dst[i] = h[i];

    if (tid < NB) {
        unsigned v = smax[tid];
        if (v) atomicMax(&tmaxb[tid], v);   // <=16 global atomics per block
    }
}

// Pass 2: half-res count (u8-packed) + raw-t sums (f32) in LDS.
// idx_k = x//2 + 60*y + 10800*b exactly; loc = x//2 + 60*y can reach 10859
// (bleed into next batch's segment) -> slow path, matches jax mode="drop".
__global__ __launch_bounds__(EVT) void k_vox(const float* __restrict__ ev, int n,
                                             unsigned int* __restrict__ ws) {
    unsigned int* cnt_acc  = ws + O_CNT;
    float*        tsum_acc = (float*)(ws + O_TSUM);
    float*        bleed    = (float*)(ws + O_BLEED);
    unsigned int* cntp     = ws + O_CNTP;
    float*        tsp      = (float*)(ws + O_TSP);

    __shared__ unsigned int c8[2700];   // 10800 u8 counts packed
    __shared__ float ts[10800];
    int tid = threadIdx.x;
    for (int i = tid; i < 2700; i += EVT) c8[i] = 0u;
    for (int i = tid; i < 10800; i += EVT) ts[i] = 0.0f;

    int chunk = (n + NBLK - 1) / NBLK;
    int start = blockIdx.x * chunk;
    int end   = min(start + chunk, n);
    int bi0   = (start < n) ? (int)ev[(size_t)5 * start + 4] : -1;
    __syncthreads();

    for (int i = start + tid; i < end; i += EVT) {
        const float* r = ev + (size_t)5 * i;
        int xi = (int)r[0], yi = (int)r[1];
        float t = r[2];
        int bi = (int)r[4];
        int loc = (xi >> 1) + (NW / 4) * yi;
        if (bi == bi0 && loc < SEG) {
            atomicAdd(&c8[loc >> 2], 1u << ((loc & 3) * 8));
            atomicAdd(&ts[loc], t);
        } else {  // rare: foreign batch or bleed; distinct addresses -> fine
            int ik = loc + SEG * bi;
            if (ik < HALF) {
                atomicAdd(&cnt_acc[ik], 1u);
                if (loc >= SEG) atomicAdd(&bleed[ik], t);  // batch bi's t in segment bi+1
                else            atomicAdd(&tsum_acc[ik], t);
            }
        }
    }
    __syncthreads();

    unsigned int* dc = cntp + (size_t)blockIdx.x * 2700;
    for (int i = tid; i < 2700; i += EVT) dc[i] = c8[i];
    float* dt = tsp + (size_t)blockIdx.x * 10800;
    for (int i = tid; i < 10800; i += EVT) dt[i] = ts[i];
}

// Merge private histograms + slow-path accumulators; emit all 5 outputs.
__global__ __launch_bounds__(256) void k_reduce(const unsigned int* __restrict__ ws,
                                                float* __restrict__ out) {
    const unsigned int* tmaxb    = ws + O_TMAX;
    const unsigned int* cont_acc = ws + O_CONT;
    const unsigned int* cnt_acc  = ws + O_CNT;
    const float*        tsum_acc = (const float*)(ws + O_TSUM);
    const float*        bleedp   = (const float*)(ws + O_BLEED);
    const int*          bmap     = (const int*)(ws + O_BMAP);
    const uint8_t*      histp    = (const uint8_t*)(ws + O_HIST);
    const uint8_t*      cntp     = (const uint8_t*)(ws + O_CNTP);
    const float*        tsp      = (const float*)(ws + O_TSP);

    __shared__ int sbmap[NBLK];
    int tid = threadIdx.x;
    sbmap[tid] = bmap[tid];
    __syncthreads();

    int v = blockIdx.x * 256 + tid;      // grid sized exactly HALF/256
    int b   = v / SEG;
    int rem = v - b * SEG;
    int i   = rem / (NW / 2);
    int j   = rem - i * (NW / 2);
    int cbl = (2 * i) * NW + 2 * j;      // local full-res base of the 2x2 block
    int cbg = b * (NH * NW) + cbl;

    unsigned c00 = cont_acc[cbg],      c01 = cont_acc[cbg + 1];
    unsigned c10 = cont_acc[cbg + NW], c11 = cont_acc[cbg + NW + 1];
    unsigned cnt = cnt_acc[v];
    float tsum = tsum_acc[v];
    float bl   = bleedp[v];

    for (int blk = 0; blk < NBLK; ++blk) {
        if (sbmap[blk] == b) {          // ~16-17 matching blocks per batch
            const uint8_t* hp = histp + (size_t)blk * 43200 + cbl;
            uint16_t r0 = *(const uint16_t*)hp;
            uint16_t r1 = *(const uint16_t*)(hp + NW);
            c00 += r0 & 0xff; c01 += r0 >> 8;
            c10 += r1 & 0xff; c11 += r1 >> 8;
            cnt  += cntp[(size_t)blk * 10800 + rem];
            tsum += tsp[(size_t)blk * 10800 + rem];
        }
    }

    float* out_cont = out;
    float* out_cnt  = out + FULL;
    float* out_tim  = out + FULL + HALF;
    float* out_dx   = out + FULL + 2 * HALF;
    float* out_dy   = out + FULL + 3 * HALF;

    out_cont[cbg]          = (float)c00;
    out_cont[cbg + 1]      = (float)c01;
    out_cont[cbg + NW]     = (float)c10;
    out_cont[cbg + NW + 1] = (float)c11;
    out_cnt[v] = (float)cnt;

    float tm  = __uint_as_float(tmaxb[b]);
    float tmp = (b > 0) ? __uint_as_float(tmaxb[b - 1]) : 1.0f;  // bleed==0 at b==0
    float s   = tsum / tm + bl / tmp;
    out_tim[v] = s / (float)(cnt == 0 ? 1u : cnt);

    out_dx[v] = (float)((int)c00 - (int)c01 + (int)c10 - (int)c11);
    out_dy[v] = (float)((int)c00 + (int)c01 - (int)c10 - (int)c11);
}

// ---------------- fallback path (R1 global-atomic version) ----------------

__global__ __launch_bounds__(256) void f_events(const float* __restrict__ ev, int n,
                                                unsigned int* __restrict__ ws) {
    unsigned int* tmaxb = ws + O_TMAX;
    int*   cont  = (int*)(ws + O_CONT);
    int*   cnt   = (int*)(ws + O_CNT);
    float* tsum  = (float*)(ws + O_TSUM);
    float* bleed = (float*)(ws + O_BLEED);
    __shared__ unsigned int smax[NB];
    if (threadIdx.x < NB) smax[threadIdx.x] = 0u;
    __syncthreads();
    int chunk = (n + gridDim.x - 1) / (int)gridDim.x;
    int start = blockIdx.x * chunk;
    int end   = min(start + chunk, n);
    for (int i = start + (int)threadIdx.x; i < end; i += (int)blockDim.x) {
        const float* r = ev + (size_t)5 * (size_t)i;
        int xi = (int)r[0], yi = (int)r[1], bi = (int)r[4];
        float t = r[2];
        atomicMax(&smax[bi], __float_as_uint(t));
        atomicAdd(&cont[xi + NW * yi + NW * NH * bi], 1);
        int loc = (xi >> 1) + (NW / 4) * yi;
        int ik  = loc + SEG * bi;
        if (ik < HALF) {
            atomicAdd(&cnt[ik], 1);
            if (loc >= SEG) atomicAdd(&bleed[ik], t);
            else            atomicAdd(&tsum[ik], t);
        }
    }
    __syncthreads();
    if (threadIdx.x < NB) {
        unsigned v = smax[threadIdx.x];
        if (v) atomicMax(&tmaxb[threadIdx.x], v);
    }
}

__global__ __launch_bounds__(256) void f_epilogue(const unsigned int* __restrict__ ws,
                                                  float* __restrict__ out) {
    const unsigned int* tmaxb = ws + O_TMAX;
    const int*   cont  = (const int*)(ws + O_CONT);
    const int*   cnt   = (const int*)(ws + O_CNT);
    const float* tsum  = (const float*)(ws + O_TSUM);
    const float* bleed = (const float*)(ws + O_BLEED);
    int v = blockIdx.x * blockDim.x + threadIdx.x;
    if (v >= HALF) return;
    int b   = v / SEG;
    int rem = v - b * SEG;
    int i   = rem / (NW / 2);
    int j   = rem - i * (NW / 2);
    int cbase = b * (NH * NW) + (2 * i) * NW + 2 * j;
    int c00 = cont[cbase],      c01 = cont[cbase + 1];
    int c10 = cont[cbase + NW], c11 = cont[cbase + NW + 1];
    float* out_cont = out;
    out_cont[cbase]          = (float)c00;
    out_cont[cbase + 1]      = (float)c01;
    out_cont[cbase + NW]     = (float)c10;
    out_cont[cbase + NW + 1] = (float)c11;
    int c = cnt[v];
    out[FULL + v] = (float)c;
    float tm  = __uint_as_float(tmaxb[b]);
    float tmp = (b > 0) ? __uint_as_float(tmaxb[b - 1]) : 1.0f;
    float s   = tsum[v] / tm + bleed[v] / tmp;
    out[FULL + HALF + v] = s / (float)(c == 0 ? 1 : c);
    out[FULL + 2 * HALF + v] = (float)(c00 - c01 + c10 - c11);
    out[FULL + 3 * HALF + v] = (float)(c00 + c01 - c10 - c11);
}

extern "C" void kernel_launch(void* const* d_in, const int* in_sizes, int n_in,
                              void* d_out, int out_size, void* d_ws, size_t ws_size,
                              hipStream_t stream) {
    const float* ev = (const float*)d_in[0];
    int n = in_sizes[0] / 5;
    unsigned int* ws = (unsigned int*)d_ws;
    float* out = (float*)d_out;

    hipLaunchKernelGGL(k_init, dim3(512), dim3(256), 0, stream, ws);

    if (ws_size >= (size_t)WS_WORDS_FAST * 4u) {
        hipLaunchKernelGGL(k_hist, dim3(NBLK), dim3(EVT), 0, stream, ev, n, ws);
        hipLaunchKernelGGL(k_vox,  dim3(NBLK), dim3(EVT), 0, stream, ev, n, ws);
        hipLaunchKernelGGL(k_reduce, dim3(HALF / 256), dim3(256), 0, stream, ws, out);
    } else {
        hipLaunchKernelGGL(f_events, dim3(2048), dim3(256), 0, stream, ev, n, ws);
        hipLaunchKernelGGL(f_epilogue, dim3((HALF + 255) / 256), dim3(256), 0, stream, ws, out);
    }
}

// Round 4
// 415.282 us; speedup vs baseline: 9.2638x; 1.0412x over previous
//
#include <hip/hip_runtime.h>
#include <stdint.h>

// B=16, H=180, W=240, N=8M events of 5 floats (x,y,t,p,b), b sorted.
constexpr int NB    = 16;
constexpr int NH    = 180;
constexpr int NW    = 240;
constexpr int FULL  = NB * NH * NW;         // 691200
constexpr int SEG   = (NH / 2) * (NW / 2);  // 10800
constexpr int HALF  = NB * SEG;             // 172800
constexpr int CELLS = NH * NW;              // 43200 full-res cells per batch
constexpr int H4W   = CELLS / 8;            // 5400 words, 4-bit packed counts
constexpr int EVT   = 1024;                 // threads per event block (16 waves)
constexpr int MAXBLK = 512;

// ---- ws layout (4-byte words) ----
constexpr int O_TMAX  = 0;                  // u32[16] float-bits, atomicMax
constexpr int O_CONT  = 16;                 // u32[FULL]  foreign-event counts
constexpr int O_TSUM  = O_CONT + FULL;      // f32[HALF]  foreign t-sums (loc<SEG)
constexpr int O_BLEED = O_TSUM + HALF;      // f32[HALF]  t-sums that bled into next batch
constexpr int ZERO_WORDS = O_BLEED + HALF;  // 1036816 words, zeroed each call
constexpr int O_BMAP  = ZERO_WORDS;         // i32[MAXBLK] block->batch
constexpr int O_PRIV  = O_BMAP + MAXBLK;    // h4[nblk][5400] then ts[nblk][10800]
constexpr int O_CNTFB = ZERO_WORDS;         // fallback-only: u32[HALF] counter

__global__ __launch_bounds__(256) void k_init(unsigned int* __restrict__ ws, int bound) {
    int i = blockIdx.x * blockDim.x + threadIdx.x;
    int stride = gridDim.x * blockDim.x;
    for (; i < bound; i += stride) ws[i] = 0u;
}

// Single event pass: 4-bit full-res hist + f32 half-res t-sums, both in LDS.
// counter output is later DERIVED from container (exact), so no half-res count
// accumulation is needed here at all.
__global__ __launch_bounds__(EVT) void k_merged(const float* __restrict__ ev, int n, int nblk,
                                                unsigned int* __restrict__ ws,
                                                unsigned int* __restrict__ h4p,
                                                float* __restrict__ tsp) {
    unsigned int* tmaxb  = ws + O_TMAX;
    unsigned int* cont_g = ws + O_CONT;
    float*        tsum_g = (float*)(ws + O_TSUM);
    float*        bleed_g= (float*)(ws + O_BLEED);
    int*          bmap   = (int*)(ws + O_BMAP);

    __shared__ unsigned int h4[H4W];    // 21.6 KB: 43200 4-bit counters
    __shared__ float        ts[SEG];    // 43.2 KB: per-half-cell t sums
    __shared__ unsigned int smax[NB];   // 64 B
    int tid = threadIdx.x;
    for (int i = tid; i < H4W; i += EVT) h4[i] = 0u;
    for (int i = tid; i < SEG; i += EVT) ts[i] = 0.0f;
    if (tid < NB) smax[tid] = 0u;

    int chunk = (n + nblk - 1) / nblk;
    int start = blockIdx.x * chunk;
    int end   = min(start + chunk, n);
    int bi0   = (start < n) ? (int)ev[(size_t)5 * start + 4] : -1;
    if (tid == 0) bmap[blockIdx.x] = bi0;
    __syncthreads();

    float tloc = 0.0f;  // t >= 0
    for (int i = start + tid; i < end; i += EVT) {
        const float* r = ev + (size_t)5 * i;
        int xi = (int)r[0], yi = (int)r[1];
        float t = r[2];
        int bi = (int)r[4];
        int cell = xi + NW * yi;
        int loc  = (xi >> 1) + (NW / 4) * yi;   // up to 10859 (y=179, x>=120)
        if (bi == bi0) {
            tloc = fmaxf(tloc, t);
            atomicAdd(&h4[cell >> 3], 1u << ((cell & 7) * 4));  // nibble ctr (max ~6 obs.)
            if (loc < SEG) {
                atomicAdd(&ts[loc], t);
            } else {  // own-batch bleed into batch bi+1's segment (rare, ~22K total)
                int ik = SEG * bi + loc;
                if (ik < HALF) atomicAdd(&bleed_g[ik], t);
            }
        } else {  // boundary-block foreign events (rare): scattered global atomics,
                  // LDS smax — NEVER same-address global atomics (R2 lesson)
            atomicMax(&smax[bi], __float_as_uint(t));
            atomicAdd(&cont_g[CELLS * bi + cell], 1u);
            int ik = SEG * bi + loc;
            if (ik < HALF) {
                if (loc < SEG) atomicAdd(&tsum_g[ik], t);
                else           atomicAdd(&bleed_g[ik], t);
            }
        }
    }

    // per-wave tmax -> one LDS atomic per wave
#pragma unroll
    for (int o = 32; o > 0; o >>= 1) tloc = fmaxf(tloc, __shfl_xor(tloc, o));
    if ((tid & 63) == 0 && bi0 >= 0) atomicMax(&smax[bi0], __float_as_uint(tloc));
    __syncthreads();

    unsigned int* dh = h4p + (size_t)blockIdx.x * H4W;
    for (int i = tid; i < H4W; i += EVT) dh[i] = h4[i];
    float* dt = tsp + (size_t)blockIdx.x * SEG;
    for (int i = tid; i < SEG; i += EVT) dt[i] = ts[i];
    if (tid < NB) {
        unsigned v = smax[tid];
        if (v) atomicMax(&tmaxb[tid], v);   // <=16 global atomics per block
    }
}

// Merge private hists + foreign accumulators; derive counter from container
// cells; emit all 5 outputs. One thread per half-res cell.
__global__ __launch_bounds__(256) void k_reduce(const unsigned int* __restrict__ ws,
                                                const unsigned int* __restrict__ h4p,
                                                const float* __restrict__ tsp,
                                                int nblk,
                                                float* __restrict__ out) {
    const unsigned int* tmaxb  = ws + O_TMAX;
    const unsigned int* cont_g = ws + O_CONT;
    const float*        tsum_g = (const float*)(ws + O_TSUM);
    const float*        bleed_g= (const float*)(ws + O_BLEED);
    const int*          bmap   = (const int*)(ws + O_BMAP);

    __shared__ int sb[MAXBLK];
    int tid = threadIdx.x;
    for (int i = tid; i < nblk; i += 256) sb[i] = bmap[i];
    __syncthreads();

    int v = blockIdx.x * 256 + tid;      // grid is exactly HALF/256 blocks
    int b   = v / SEG;
    int rem = v - b * SEG;
    int i   = rem / (NW / 2);
    int j   = rem - i * (NW / 2);
    int cbl = 480 * i + 2 * j;           // local cell of C[2i][2j]
    int cbg = CELLS * b + cbl;

    unsigned c00 = cont_g[cbg],      c01 = cont_g[cbg + 1];
    unsigned c10 = cont_g[cbg + NW], c11 = cont_g[cbg + NW + 1];
    float tsum = tsum_g[v];

    // counter[b,i,j] = C[b,2i,2j]+C[b,2i,2j+1] + odd-row shifted pair:
    //   j>=60          -> C[b,2i+1,2j-120..]   (ocell = cbl+120)
    //   j<60 && i>=1   -> C[b,2i-1,2j+120..]   (ocell = cbl-120)
    //   j<60 && i==0   -> C[b-1,179,2j+120..]  (prev batch bleed; none for b==0)
    bool prev = false;
    int ocell;
    if (j >= 60)      ocell = cbl + 120;
    else if (i >= 1)  ocell = cbl - 120;
    else { prev = true; ocell = 43080 + 2 * j; }
    unsigned oc = 0;
    if (!prev)            oc = cont_g[CELLS * b + ocell] + cont_g[CELLS * b + ocell + 1];
    else if (b >= 1)      oc = cont_g[CELLS * (b - 1) + ocell] + cont_g[CELLS * (b - 1) + ocell + 1];

    int w0i = cbl >> 3, nib = (cbl & 7) * 4;   // cbl even -> both nibbles in one word
    int w1i = w0i + 30;                        // +240 cells = +30 words
    int owi = ocell >> 3, onib = (ocell & 7) * 4;

    for (int blk = 0; blk < nblk; ++blk) {
        int sbb = sb[blk];
        if (sbb == b) {
            const unsigned int* hp = h4p + (size_t)blk * H4W;
            unsigned w0 = hp[w0i], w1 = hp[w1i];
            c00 += (w0 >> nib) & 15u;  c01 += (w0 >> (nib + 4)) & 15u;
            c10 += (w1 >> nib) & 15u;  c11 += (w1 >> (nib + 4)) & 15u;
            if (!prev) {
                unsigned wo = hp[owi];
                oc += ((wo >> onib) & 15u) + ((wo >> (onib + 4)) & 15u);
            }
            tsum += tsp[(size_t)blk * SEG + rem];
        } else if (prev && b >= 1 && sbb == b - 1) {
            unsigned wo = h4p[(size_t)blk * H4W + owi];
            oc += ((wo >> onib) & 15u) + ((wo >> (onib + 4)) & 15u);
        }
    }
    unsigned cnt = c00 + c01 + oc;

    float* out_cont = out;
    float* out_cnt  = out + FULL;
    float* out_tim  = out + FULL + HALF;
    float* out_dx   = out + FULL + 2 * HALF;
    float* out_dy   = out + FULL + 3 * HALF;

    out_cont[cbg]          = (float)c00;
    out_cont[cbg + 1]      = (float)c01;
    out_cont[cbg + NW]     = (float)c10;
    out_cont[cbg + NW + 1] = (float)c11;
    out_cnt[v] = (float)cnt;

    float tm  = __uint_as_float(tmaxb[b]);
    float tmp = (b > 0) ? __uint_as_float(tmaxb[b - 1]) : 1.0f;  // bleed==0 at b==0
    float s   = tsum / tm + bleed_g[v] / tmp;
    out_tim[v] = s / (float)(cnt == 0 ? 1u : cnt);

    out_dx[v] = (float)((int)c00 - (int)c01 + (int)c10 - (int)c11);
    out_dy[v] = (float)((int)c00 + (int)c01 - (int)c10 - (int)c11);
}

// ---------------- fallback (global-atomic R1 path; ws too small) ----------------

__global__ __launch_bounds__(256) void f_events(const float* __restrict__ ev, int n,
                                                unsigned int* __restrict__ ws) {
    unsigned int* tmaxb = ws + O_TMAX;
    int*   cont  = (int*)(ws + O_CONT);
    int*   cnt   = (int*)(ws + O_CNTFB);
    float* tsum  = (float*)(ws + O_TSUM);
    float* bleed = (float*)(ws + O_BLEED);
    __shared__ unsigned int smax[NB];
    if (threadIdx.x < NB) smax[threadIdx.x] = 0u;
    __syncthreads();
    int chunk = (n + gridDim.x - 1) / (int)gridDim.x;
    int start = blockIdx.x * chunk;
    int end   = min(start + chunk, n);
    for (int i = start + (int)threadIdx.x; i < end; i += (int)blockDim.x) {
        const float* r = ev + (size_t)5 * (size_t)i;
        int xi = (int)r[0], yi = (int)r[1], bi = (int)r[4];
        float t = r[2];
        atomicMax(&smax[bi], __float_as_uint(t));
        atomicAdd(&cont[xi + NW * yi + CELLS * bi], 1);
        int loc = (xi >> 1) + (NW / 4) * yi;
        int ik  = loc + SEG * bi;
        if (ik < HALF) {
            atomicAdd(&cnt[ik], 1);
            if (loc >= SEG) atomicAdd(&bleed[ik], t);
            else            atomicAdd(&tsum[ik], t);
        }
    }
    __syncthreads();
    if (threadIdx.x < NB) {
        unsigned v = smax[threadIdx.x];
        if (v) atomicMax(&tmaxb[threadIdx.x], v);
    }
}

__global__ __launch_bounds__(256) void f_epilogue(const unsigned int* __restrict__ ws,
                                                  float* __restrict__ out) {
    const unsigned int* tmaxb = ws + O_TMAX;
    const int*   cont  = (const int*)(ws + O_CONT);
    const int*   cnt   = (const int*)(ws + O_CNTFB);
    const float* tsum  = (const float*)(ws + O_TSUM);
    const float* bleed = (const float*)(ws + O_BLEED);
    int v = blockIdx.x * blockDim.x + threadIdx.x;
    if (v >= HALF) return;
    int b   = v / SEG;
    int rem = v - b * SEG;
    int i   = rem / (NW / 2);
    int j   = rem - i * (NW / 2);
    int cbase = b * CELLS + 480 * i + 2 * j;
    int c00 = cont[cbase],      c01 = cont[cbase + 1];
    int c10 = cont[cbase + NW], c11 = cont[cbase + NW + 1];
    out[cbase]          = (float)c00;
    out[cbase + 1]      = (float)c01;
    out[cbase + NW]     = (float)c10;
    out[cbase + NW + 1] = (float)c11;
    int c = cnt[v];
    out[FULL + v] = (float)c;
    float tm  = __uint_as_float(tmaxb[b]);
    float tmp = (b > 0) ? __uint_as_float(tmaxb[b - 1]) : 1.0f;
    float s   = tsum[v] / tm + bleed[v] / tmp;
    out[FULL + HALF + v] = s / (float)(c == 0 ? 1 : c);
    out[FULL + 2 * HALF + v] = (float)(c00 - c01 + c10 - c11);
    out[FULL + 3 * HALF + v] = (float)(c00 + c01 - c10 - c11);
}

extern "C" void kernel_launch(void* const* d_in, const int* in_sizes, int n_in,
                              void* d_out, int out_size, void* d_ws, size_t ws_size,
                              hipStream_t stream) {
    const float* ev = (const float*)d_in[0];
    int n = in_sizes[0] / 5;
    unsigned int* ws = (unsigned int*)d_ws;
    float* out = (float*)d_out;

    size_t need512 = (size_t)(O_PRIV + 512 * (H4W + SEG)) * 4u;  // ~37.3 MB
    size_t need256 = (size_t)(O_PRIV + 256 * (H4W + SEG)) * 4u;  // ~20.7 MB
    int nblk = (ws_size >= need512) ? 512 : ((ws_size >= need256) ? 256 : 0);

    if (nblk) {
        unsigned int* h4p = ws + O_PRIV;
        float*        tsp = (float*)(ws + O_PRIV + nblk * H4W);
        hipLaunchKernelGGL(k_init, dim3(512), dim3(256), 0, stream, ws, ZERO_WORDS);
        hipLaunchKernelGGL(k_merged, dim3(nblk), dim3(EVT), 0, stream, ev, n, nblk, ws, h4p, tsp);
        hipLaunchKernelGGL(k_reduce, dim3(HALF / 256), dim3(256), 0, stream, ws, h4p, tsp, nblk, out);
    } else {
        hipLaunchKernelGGL(k_init, dim3(512), dim3(256), 0, stream, ws, ZERO_WORDS + HALF);
        hipLaunchKernelGGL(f_events, dim3(2048), dim3(256), 0, stream, ev, n, ws);
        hipLaunchKernelGGL(f_epilogue, dim3((HALF + 255) / 256), dim3(256), 0, stream, ws, out);
    }
}

// Round 5
// 313.409 us; speedup vs baseline: 12.2750x; 1.3250x over previous
//
#include <hip/hip_runtime.h>
#include <stdint.h>

// B=16, H=180, W=240, N=8M events of 5 floats (x,y,t,p,b), b sorted.
constexpr int NB    = 16;
constexpr int NH    = 180;
constexpr int NW    = 240;
constexpr int FULL  = NB * NH * NW;         // 691200
constexpr int SEG   = (NH / 2) * (NW / 2);  // 10800
constexpr int HALF  = NB * SEG;             // 172800
constexpr int CELLS = NH * NW;              // 43200 full-res cells per batch
constexpr int H4W   = CELLS / 8;            // 5400 words, 4-bit packed counts
constexpr int EVT   = 512;                  // threads per event block (8 waves)
constexpr int MAXBLK = 512;
constexpr int RT    = 43;                   // reduce tiles per batch (43*256 >= SEG)

// ---- ws layout (4-byte words) ----
constexpr int O_TMAX  = 0;                  // u32[16] float-bits, atomicMax
constexpr int O_CONT  = 16;                 // u32[FULL]  foreign-event counts
constexpr int O_TSUM  = O_CONT + FULL;      // f32[HALF]  foreign t-sums (loc<SEG)
constexpr int O_BLEED = O_TSUM + HALF;      // f32[HALF]  t-sums bled into next batch
constexpr int ZERO_WORDS = O_BLEED + HALF;  // zeroed each call
constexpr int O_BMAP  = ZERO_WORDS;         // i32[MAXBLK] block->batch
constexpr int O_PRIV  = O_BMAP + MAXBLK;    // h4[nblk][5400] then ts[nblk][10800]
constexpr int O_CNTFB = ZERO_WORDS;         // fallback-only: u32[HALF] counter

__global__ __launch_bounds__(256) void k_init(unsigned int* __restrict__ ws, int bound) {
    int i = blockIdx.x * blockDim.x + threadIdx.x;
    int stride = gridDim.x * blockDim.x;
    for (; i < bound; i += stride) ws[i] = 0u;
}

// Single event pass: 4-bit full-res hist + f32 half-res t-sums in LDS.
// 4 events per thread-iteration via 5 float4 loads -> ~5x MLP (R4 lesson:
// VGPR=8 scalar path was load-latency serialized at 1.5 B/cy/CU).
__global__ __launch_bounds__(EVT) void k_merged(const float* __restrict__ ev, int n, int nblk,
                                                unsigned int* __restrict__ ws,
                                                unsigned int* __restrict__ h4p,
                                                float* __restrict__ tsp) {
    unsigned int* tmaxb  = ws + O_TMAX;
    unsigned int* cont_g = ws + O_CONT;
    float*        tsum_g = (float*)(ws + O_TSUM);
    float*        bleed_g= (float*)(ws + O_BLEED);
    int*          bmap   = (int*)(ws + O_BMAP);

    __shared__ unsigned int h4[H4W];    // 21.6 KB: 43200 4-bit counters
    __shared__ float        ts[SEG];    // 43.2 KB
    __shared__ unsigned int smax[NB];
    int tid = threadIdx.x;
    for (int i = tid; i < H4W; i += EVT) h4[i] = 0u;
    for (int i = tid; i < SEG; i += EVT) ts[i] = 0.0f;
    if (tid < NB) smax[tid] = 0u;

    int chunk = (((n + nblk - 1) / nblk) + 3) & ~3;   // multiple of 4
    int start = blockIdx.x * chunk;
    int end   = min(start + chunk, n);
    int bi0   = (start < n && start < end) ? (int)ev[(size_t)5 * start + 4] : -1;
    if (tid == 0) bmap[blockIdx.x] = bi0;
    __syncthreads();

    float tloc = 0.0f;  // t >= 0

    auto proc = [&](float fx, float fy, float t, float fb) {
        int xi = (int)fx, yi = (int)fy, bi = (int)fb;
        int cell = xi + NW * yi;
        int loc  = (xi >> 1) + (NW / 4) * yi;   // up to 10859 (y=179, x>=120)
        if (bi == bi0) {
            tloc = fmaxf(tloc, t);
            atomicAdd(&h4[cell >> 3], 1u << ((cell & 7) * 4));
            if (loc < SEG) {
                atomicAdd(&ts[loc], t);
            } else {  // own-batch bleed into next batch's segment (rare)
                int ik = SEG * bi + loc;
                if (ik < HALF) atomicAdd(&bleed_g[ik], t);
            }
        } else {  // boundary-block foreign events: scattered global atomics,
                  // LDS smax — NEVER same-address global atomics (R2 lesson)
            atomicMax(&smax[bi], __float_as_uint(t));
            atomicAdd(&cont_g[CELLS * bi + cell], 1u);
            int ik = SEG * bi + loc;
            if (ik < HALF) {
                if (loc < SEG) atomicAdd(&tsum_g[ik], t);
                else           atomicAdd(&bleed_g[ik], t);
            }
        }
    };

    if (start < end) {
        int ng = (end - start) >> 2;            // full groups of 4 events
        const float4* e4 = (const float4*)ev;
        size_t qbase = (size_t)5 * (size_t)(start >> 2);
        for (int g = tid; g < ng; g += EVT) {
            size_t qb = qbase + (size_t)5 * g;
            float4 q0 = e4[qb], q1 = e4[qb + 1], q2 = e4[qb + 2],
                   q3 = e4[qb + 3], q4 = e4[qb + 4];
            // [x0 y0 t0 p0][b0 x1 y1 t1][p1 b1 x2 y2][t2 p2 b2 x3][y3 t3 p3 b3]
            proc(q0.x, q0.y, q0.z, q1.x);
            proc(q1.y, q1.z, q1.w, q2.y);
            proc(q2.z, q2.w, q3.x, q3.z);
            proc(q3.w, q4.x, q4.y, q4.w);
        }
        for (int i = start + (ng << 2) + tid; i < end; i += EVT) {  // <=3 tail events
            const float* r = ev + (size_t)5 * i;
            proc(r[0], r[1], r[2], r[4]);
        }
    }

    // per-wave tmax -> one LDS atomic per wave
#pragma unroll
    for (int o = 32; o > 0; o >>= 1) tloc = fmaxf(tloc, __shfl_xor(tloc, o));
    if ((tid & 63) == 0 && bi0 >= 0) atomicMax(&smax[bi0], __float_as_uint(tloc));
    __syncthreads();

    unsigned int* dh = h4p + (size_t)blockIdx.x * H4W;
    for (int i = tid; i < H4W; i += EVT) dh[i] = h4[i];
    float* dt = tsp + (size_t)blockIdx.x * SEG;
    for (int i = tid; i < SEG; i += EVT) dt[i] = ts[i];
    if (tid < NB) {
        unsigned v = smax[tid];
        if (v) atomicMax(&tmaxb[tid], v);   // <=16 global atomics per block
    }
}

// Merge private hists + foreign accumulators; derive counter from container.
// Grid = NB * RT blocks; each block serves one batch tile -> build the batch's
// match-list in LDS once, then loop branch-free (R4 lesson: 512-iter branchy
// loop serialized its scattered loads).
__global__ __launch_bounds__(256) void k_reduce(const unsigned int* __restrict__ ws,
                                                const unsigned int* __restrict__ h4p,
                                                const float* __restrict__ tsp,
                                                int nblk,
                                                float* __restrict__ out) {
    const unsigned int* tmaxb  = ws + O_TMAX;
    const unsigned int* cont_g = ws + O_CONT;
    const float*        tsum_g = (const float*)(ws + O_TSUM);
    const float*        bleed_g= (const float*)(ws + O_BLEED);
    const int*          bmap   = (const int*)(ws + O_BMAP);

    __shared__ int lst[MAXBLK], lstp[MAXBLK];
    __shared__ int lc, lcp;
    int tid  = threadIdx.x;
    int b    = blockIdx.x / RT;
    int tile = blockIdx.x - b * RT;
    if (tid == 0) { lc = 0; lcp = 0; }
    __syncthreads();
    for (int i = tid; i < nblk; i += 256) {
        int sbb = bmap[i];
        if (sbb == b)            lst[atomicAdd(&lc, 1)]  = i;
        else if (sbb == b - 1)   lstp[atomicAdd(&lcp, 1)] = i;
    }
    __syncthreads();
    int nl = lc, nlp = lcp;

    int rem = tile * 256 + tid;
    if (rem >= SEG) return;
    int v = b * SEG + rem;
    int i = rem / (NW / 2);
    int j = rem - i * (NW / 2);
    int cbl = 480 * i + 2 * j;           // local cell of C[2i][2j]
    int cbg = CELLS * b + cbl;

    unsigned c00 = cont_g[cbg],      c01 = cont_g[cbg + 1];
    unsigned c10 = cont_g[cbg + NW], c11 = cont_g[cbg + NW + 1];
    float tsum = tsum_g[v];

    // counter[b,i,j] = C[b,2i,2j]+C[b,2i,2j+1] + odd-row shifted pair:
    //   j>=60        -> C[b,2i+1,2j-120..]
    //   j<60 && i>=1 -> C[b,2i-1,2j+120..]
    //   j<60 && i==0 -> C[b-1,179,2j+120..] (prev-batch bleed; none for b==0)
    bool prev = false;
    int ocell;
    if (j >= 60)      ocell = cbl + 120;
    else if (i >= 1)  ocell = cbl - 120;
    else { prev = true; ocell = 43080 + 2 * j; }
    unsigned oc = 0;
    if (!prev)       oc = cont_g[CELLS * b + ocell] + cont_g[CELLS * b + ocell + 1];
    else if (b >= 1) oc = cont_g[CELLS * (b - 1) + ocell] + cont_g[CELLS * (b - 1) + ocell + 1];

    int w0i = cbl >> 3, nib = (cbl & 7) * 4;   // cbl even -> pair in one word
    int w1i = w0i + 30;                        // +240 cells = +30 words
    int owi = ocell >> 3, onib = (ocell & 7) * 4;

    for (int k = 0; k < nl; ++k) {
        int blk = lst[k];
        const unsigned int* hp = h4p + (size_t)blk * H4W;
        unsigned w0 = hp[w0i], w1 = hp[w1i], wo = hp[owi];
        c00 += (w0 >> nib) & 15u;  c01 += (w0 >> (nib + 4)) & 15u;
        c10 += (w1 >> nib) & 15u;  c11 += (w1 >> (nib + 4)) & 15u;
        if (!prev) oc += ((wo >> onib) & 15u) + ((wo >> (onib + 4)) & 15u);
        tsum += tsp[(size_t)blk * SEG + rem];
    }
    if (prev && b >= 1) {
        for (int k = 0; k < nlp; ++k) {
            unsigned wo = h4p[(size_t)lstp[k] * H4W + owi];
            oc += ((wo >> onib) & 15u) + ((wo >> (onib + 4)) & 15u);
        }
    }
    unsigned cnt = c00 + c01 + oc;

    float* out_cont = out;
    out_cont[cbg]          = (float)c00;
    out_cont[cbg + 1]      = (float)c01;
    out_cont[cbg + NW]     = (float)c10;
    out_cont[cbg + NW + 1] = (float)c11;
    out[FULL + v] = (float)cnt;

    float tm  = __uint_as_float(tmaxb[b]);
    float tmp = (b > 0) ? __uint_as_float(tmaxb[b - 1]) : 1.0f;  // bleed==0 at b==0
    float s   = tsum / tm + bleed_g[v] / tmp;
    out[FULL + HALF + v] = s / (float)(cnt == 0 ? 1u : cnt);

    out[FULL + 2 * HALF + v] = (float)((int)c00 - (int)c01 + (int)c10 - (int)c11);
    out[FULL + 3 * HALF + v] = (float)((int)c00 + (int)c01 - (int)c10 - (int)c11);
}

// ---------------- fallback (global-atomic R1 path; ws too small) ----------------

__global__ __launch_bounds__(256) void f_events(const float* __restrict__ ev, int n,
                                                unsigned int* __restrict__ ws) {
    unsigned int* tmaxb = ws + O_TMAX;
    int*   cont  = (int*)(ws + O_CONT);
    int*   cnt   = (int*)(ws + O_CNTFB);
    float* tsum  = (float*)(ws + O_TSUM);
    float* bleed = (float*)(ws + O_BLEED);
    __shared__ unsigned int smax[NB];
    if (threadIdx.x < NB) smax[threadIdx.x] = 0u;
    __syncthreads();
    int chunk = (n + gridDim.x - 1) / (int)gridDim.x;
    int start = blockIdx.x * chunk;
    int end   = min(start + chunk, n);
    for (int i = start + (int)threadIdx.x; i < end; i += (int)blockDim.x) {
        const float* r = ev + (size_t)5 * (size_t)i;
        int xi = (int)r[0], yi = (int)r[1], bi = (int)r[4];
        float t = r[2];
        atomicMax(&smax[bi], __float_as_uint(t));
        atomicAdd(&cont[xi + NW * yi + CELLS * bi], 1);
        int loc = (xi >> 1) + (NW / 4) * yi;
        int ik  = loc + SEG * bi;
        if (ik < HALF) {
            atomicAdd(&cnt[ik], 1);
            if (loc >= SEG) atomicAdd(&bleed[ik], t);
            else            atomicAdd(&tsum[ik], t);
        }
    }
    __syncthreads();
    if (threadIdx.x < NB) {
        unsigned v = smax[threadIdx.x];
        if (v) atomicMax(&tmaxb[threadIdx.x], v);
    }
}

__global__ __launch_bounds__(256) void f_epilogue(const unsigned int* __restrict__ ws,
                                                  float* __restrict__ out) {
    const unsigned int* tmaxb = ws + O_TMAX;
    const int*   cont  = (const int*)(ws + O_CONT);
    const int*   cnt   = (const int*)(ws + O_CNTFB);
    const float* tsum  = (const float*)(ws + O_TSUM);
    const float* bleed = (const float*)(ws + O_BLEED);
    int v = blockIdx.x * blockDim.x + threadIdx.x;
    if (v >= HALF) return;
    int b   = v / SEG;
    int rem = v - b * SEG;
    int i   = rem / (NW / 2);
    int j   = rem - i * (NW / 2);
    int cbase = b * CELLS + 480 * i + 2 * j;
    int c00 = cont[cbase],      c01 = cont[cbase + 1];
    int c10 = cont[cbase + NW], c11 = cont[cbase + NW + 1];
    out[cbase]          = (float)c00;
    out[cbase + 1]      = (float)c01;
    out[cbase + NW]     = (float)c10;
    out[cbase + NW + 1] = (float)c11;
    int c = cnt[v];
    out[FULL + v] = (float)c;
    float tm  = __uint_as_float(tmaxb[b]);
    float tmp = (b > 0) ? __uint_as_float(tmaxb[b - 1]) : 1.0f;
    float s   = tsum[v] / tm + bleed[v] / tmp;
    out[FULL + HALF + v] = s / (float)(c == 0 ? 1 : c);
    out[FULL + 2 * HALF + v] = (float)(c00 - c01 + c10 - c11);
    out[FULL + 3 * HALF + v] = (float)(c00 + c01 - c10 - c11);
}

extern "C" void kernel_launch(void* const* d_in, const int* in_sizes, int n_in,
                              void* d_out, int out_size, void* d_ws, size_t ws_size,
                              hipStream_t stream) {
    const float* ev = (const float*)d_in[0];
    int n = in_sizes[0] / 5;
    unsigned int* ws = (unsigned int*)d_ws;
    float* out = (float*)d_out;

    size_t need512 = (size_t)(O_PRIV + 512 * (H4W + SEG)) * 4u;  // ~37.3 MB
    size_t need256 = (size_t)(O_PRIV + 256 * (H4W + SEG)) * 4u;  // ~20.7 MB
    int nblk = (ws_size >= need512) ? 512 : ((ws_size >= need256) ? 256 : 0);

    if (nblk) {
        unsigned int* h4p = ws + O_PRIV;
        float*        tsp = (float*)(ws + O_PRIV + nblk * H4W);
        hipLaunchKernelGGL(k_init, dim3(512), dim3(256), 0, stream, ws, ZERO_WORDS);
        hipLaunchKernelGGL(k_merged, dim3(nblk), dim3(EVT), 0, stream, ev, n, nblk, ws, h4p, tsp);
        hipLaunchKernelGGL(k_reduce, dim3(NB * RT), dim3(256), 0, stream, ws, h4p, tsp, nblk, out);
    } else {
        hipLaunchKernelGGL(k_init, dim3(512), dim3(256), 0, stream, ws, ZERO_WORDS + HALF);
        hipLaunchKernelGGL(f_events, dim3(2048), dim3(256), 0, stream, ev, n, ws);
        hipLaunchKernelGGL(f_epilogue, dim3((HALF + 255) / 256), dim3(256), 0, stream, ws, out);
    }
}

// Round 6
// 256.765 us; speedup vs baseline: 14.9830x; 1.2206x over previous
//
#include <hip/hip_runtime.h>
#include <stdint.h>

// B=16, H=180, W=240, N=8M events of 5 floats (x,y,t,p,b), b sorted.
constexpr int NB    = 16;
constexpr int NH    = 180;
constexpr int NW    = 240;
constexpr int FULL  = NB * NH * NW;         // 691200
constexpr int SEG   = (NH / 2) * (NW / 2);  // 10800
constexpr int HALF  = NB * SEG;             // 172800
constexpr int CELLS = NH * NW;              // 43200 full-res cells per batch
constexpr int H4W   = CELLS / 8;            // 5400 words, 4-bit packed counts
constexpr int EVT   = 512;                  // threads per event block (8 waves)
constexpr int NBPB  = 32;                   // event blocks per batch (batch-aligned!)
constexpr int NBLK  = NB * NBPB;            // 512 event blocks
constexpr int RT    = 43;                   // reduce tiles per batch (43*256 >= SEG)

// ---- ws layout (4-byte words) ----
constexpr int O_TMAX  = 0;                  // u32[16] float-bits, atomicMax
constexpr int O_CONT  = 16;                 // u32[FULL]   (fast path: unused-but-zeroed; kept for fallback)
constexpr int O_TSUM  = O_CONT + FULL;      // f32[HALF]  fallback tsum
constexpr int O_BLEED = O_TSUM + HALF;      // f32[HALF]  t-sums bled into next batch
constexpr int ZERO_WORDS = O_BLEED + HALF;  // zeroed each call
constexpr int O_BND   = ZERO_WORDS;         // i32[17] batch boundaries (k_bounds writes all)
constexpr int O_PRIV  = O_BND + 32;         // h4[NBLK][5400] then ts[NBLK][10800]
constexpr int O_CNTFB = ZERO_WORDS;         // fallback-only: u32[HALF] counter (aliases O_BND+)

__global__ __launch_bounds__(256) void k_init(unsigned int* __restrict__ ws, int bound) {
    int i = blockIdx.x * blockDim.x + threadIdx.x;
    int stride = gridDim.x * blockDim.x;
    for (; i < bound; i += stride) ws[i] = 0u;
}

// 17 parallel binary searches: bnd[b] = first i with ev[5i+4] >= b.
__global__ __launch_bounds__(64) void k_bounds(const float* __restrict__ ev, int n,
                                               int* __restrict__ bnd) {
    int b = threadIdx.x;
    if (b > NB) return;
    int lo = 0, hi = n;
    while (lo < hi) {
        int mid = (lo + hi) >> 1;
        float v = ev[(size_t)5 * mid + 4];
        if (v < (float)b) lo = mid + 1; else hi = mid;
    }
    bnd[b] = lo;
}

// Single event pass, batch-aligned ranges: block k serves batch k/32, slice
// k%32 of that batch -> every event is own-batch (R5 lesson: the ~15 boundary
// blocks with global-atomic foreign paths straggled to 2.5x and set the wall
// clock). 4-bit full-res hist + f32 half-res t-sums in LDS; 2x4-event groups
// per iteration = 10 float4 loads in flight.
__global__ __launch_bounds__(EVT) void k_merged(const float* __restrict__ ev,
                                                const int* __restrict__ bnd,
                                                unsigned int* __restrict__ ws,
                                                unsigned int* __restrict__ h4p,
                                                float* __restrict__ tsp) {
    unsigned int* tmaxb   = ws + O_TMAX;
    float*        bleed_g = (float*)(ws + O_BLEED);

    __shared__ unsigned int h4[H4W];    // 21.6 KB: 43200 4-bit counters
    __shared__ float        ts[SEG];    // 43.2 KB
    __shared__ unsigned int bsm;        // block tmax
    int tid = threadIdx.x;
    for (int i = tid; i < H4W; i += EVT) h4[i] = 0u;
    for (int i = tid; i < SEG; i += EVT) ts[i] = 0.0f;
    if (tid == 0) bsm = 0u;

    int b0 = blockIdx.x >> 5;           // this block's batch (exact)
    int r  = blockIdx.x & (NBPB - 1);
    int sb = bnd[b0], eb = bnd[b0 + 1];
    long long len = (long long)(eb - sb);
    int s = sb + (int)(len * r / NBPB);
    int e = sb + (int)(len * (r + 1) / NBPB);
    __syncthreads();

    float tloc = 0.0f;  // t >= 0

    auto proc = [&](float fx, float fy, float t) {
        int xi = (int)fx, yi = (int)fy;
        int cell = xi + NW * yi;
        int loc  = (xi >> 1) + (NW / 4) * yi;   // up to 10859 (y=179, x>=120)
        tloc = fmaxf(tloc, t);
        atomicAdd(&h4[cell >> 3], 1u << ((cell & 7) * 4));
        if (loc < SEG) {
            atomicAdd(&ts[loc], t);
        } else {  // own-batch bleed into next batch's segment (rare, global)
            int ik = SEG * b0 + loc;
            if (ik < HALF) atomicAdd(&bleed_g[ik], t);
        }
    };

    if (s < e) {
        int as_ = min((s + 3) & ~3, e);          // align to 4 for float4 view
        for (int i = s + tid; i < as_; i += EVT) {   // <=3 prologue events
            const float* rr = ev + (size_t)5 * i;
            proc(rr[0], rr[1], rr[2]);
        }
        int ng = (e - as_) >> 2;                 // full groups of 4 events
        const float4* e4 = (const float4*)ev;
        size_t qbase = (size_t)5 * (size_t)(as_ >> 2);
        for (int g = tid; g < ng; g += 2 * EVT) {
            int g2 = g + EVT;
            size_t qb = qbase + (size_t)5 * g;
            float4 q0 = e4[qb], q1 = e4[qb + 1], q2 = e4[qb + 2],
                   q3 = e4[qb + 3], q4 = e4[qb + 4];
            // [x0 y0 t0 p0][b0 x1 y1 t1][p1 b1 x2 y2][t2 p2 b2 x3][y3 t3 p3 b3]
            if (g2 < ng) {
                size_t qc = qbase + (size_t)5 * g2;
                float4 p0 = e4[qc], p1 = e4[qc + 1], p2 = e4[qc + 2],
                       p3 = e4[qc + 3], p4 = e4[qc + 4];
                proc(q0.x, q0.y, q0.z);
                proc(q1.y, q1.z, q1.w);
                proc(q2.z, q2.w, q3.x);
                proc(q3.w, q4.x, q4.y);
                proc(p0.x, p0.y, p0.z);
                proc(p1.y, p1.z, p1.w);
                proc(p2.z, p2.w, p3.x);
                proc(p3.w, p4.x, p4.y);
            } else {
                proc(q0.x, q0.y, q0.z);
                proc(q1.y, q1.z, q1.w);
                proc(q2.z, q2.w, q3.x);
                proc(q3.w, q4.x, q4.y);
            }
        }
        for (int i = as_ + (ng << 2) + tid; i < e; i += EVT) {  // <=3 tail events
            const float* rr = ev + (size_t)5 * i;
            proc(rr[0], rr[1], rr[2]);
        }
    }

    // per-wave tmax -> one LDS atomic per wave -> one global atomic per block
#pragma unroll
    for (int o = 32; o > 0; o >>= 1) tloc = fmaxf(tloc, __shfl_xor(tloc, o));
    if ((tid & 63) == 0) atomicMax(&bsm, __float_as_uint(tloc));
    __syncthreads();

    unsigned int* dh = h4p + (size_t)blockIdx.x * H4W;
    for (int i = tid; i < H4W; i += EVT) dh[i] = h4[i];
    float* dt = tsp + (size_t)blockIdx.x * SEG;
    for (int i = tid; i < SEG; i += EVT) dt[i] = ts[i];
    if (tid == 0 && bsm) atomicMax(&tmaxb[b0], bsm);  // 32 per address total
}

// Merge the 32 per-batch private hists; derive counter from container; emit
// all 5 outputs. Source list is the constant range [32b, 32b+32) -> constant
// trip count, unroll 8 for load batching (R4/R5 lesson: this loop was
// latency-serialized).
__global__ __launch_bounds__(256) void k_reduce(const unsigned int* __restrict__ ws,
                                                const unsigned int* __restrict__ h4p,
                                                const float* __restrict__ tsp,
                                                float* __restrict__ out) {
    const unsigned int* tmaxb   = ws + O_TMAX;
    const float*        bleed_g = (const float*)(ws + O_BLEED);

    int tid  = threadIdx.x;
    int b    = blockIdx.x / RT;
    int tile = blockIdx.x - b * RT;

    int rem = tile * 256 + tid;
    if (rem >= SEG) return;
    int v = b * SEG + rem;
    int i = rem / (NW / 2);
    int j = rem - i * (NW / 2);
    int cbl = 480 * i + 2 * j;           // local cell of C[2i][2j]
    int cbg = CELLS * b + cbl;

    unsigned c00 = 0, c01 = 0, c10 = 0, c11 = 0, oc = 0;
    float tsum = 0.0f;

    // counter[b,i,j] = C[b,2i,2j]+C[b,2i,2j+1] + odd-row shifted pair:
    //   j>=60        -> C[b,2i+1,2j-120..]
    //   j<60 && i>=1 -> C[b,2i-1,2j+120..]
    //   j<60 && i==0 -> C[b-1,179,2j+120..] (prev-batch bleed; none for b==0)
    bool prev = false;
    int ocell;
    if (j >= 60)      ocell = cbl + 120;
    else if (i >= 1)  ocell = cbl - 120;
    else { prev = true; ocell = 43080 + 2 * j; }

    int w0i = cbl >> 3, nib = (cbl & 7) * 4;   // cbl even -> pair in one word
    int w1i = w0i + 30;                        // +240 cells = +30 words
    int owi = ocell >> 3, onib = (ocell & 7) * 4;

    int base = b << 5;
#pragma unroll 8
    for (int k = 0; k < NBPB; ++k) {
        const unsigned int* hp = h4p + (size_t)(base + k) * H4W;
        unsigned w0 = hp[w0i], w1 = hp[w1i], wo = hp[owi];
        float tv = tsp[(size_t)(base + k) * SEG + rem];
        c00 += (w0 >> nib) & 15u;  c01 += (w0 >> (nib + 4)) & 15u;
        c10 += (w1 >> nib) & 15u;  c11 += (w1 >> (nib + 4)) & 15u;
        oc  += ((wo >> onib) & 15u) + ((wo >> (onib + 4)) & 15u);
        tsum += tv;
    }
    if (prev) {
        oc = 0;                               // fast-loop oc was for batch b; discard
        if (b >= 1) {
            int pb = (b - 1) << 5;
#pragma unroll 8
            for (int k = 0; k < NBPB; ++k) {
                unsigned wo = h4p[(size_t)(pb + k) * H4W + owi];
                oc += ((wo >> onib) & 15u) + ((wo >> (onib + 4)) & 15u);
            }
        }
    }
    unsigned cnt = c00 + c01 + oc;

    out[cbg]          = (float)c00;
    out[cbg + 1]      = (float)c01;
    out[cbg + NW]     = (float)c10;
    out[cbg + NW + 1] = (float)c11;
    out[FULL + v] = (float)cnt;

    float tm = __uint_as_float(tmaxb[b]);
    if (!(tm > 0.0f)) tm = 1.0f;                       // empty-batch guard
    float tmp = (b > 0) ? __uint_as_float(tmaxb[b - 1]) : 1.0f;
    if (!(tmp > 0.0f)) tmp = 1.0f;
    float s = tsum / tm + bleed_g[v] / tmp;
    out[FULL + HALF + v] = s / (float)(cnt == 0 ? 1u : cnt);

    out[FULL + 2 * HALF + v] = (float)((int)c00 - (int)c01 + (int)c10 - (int)c11);
    out[FULL + 3 * HALF + v] = (float)((int)c00 + (int)c01 - (int)c10 - (int)c11);
}

// ---------------- fallback (global-atomic R1 path; ws too small) ----------------

__global__ __launch_bounds__(256) void f_events(const float* __restrict__ ev, int n,
                                                unsigned int* __restrict__ ws) {
    unsigned int* tmaxb = ws + O_TMAX;
    int*   cont  = (int*)(ws + O_CONT);
    int*   cnt   = (int*)(ws + O_CNTFB + 32);
    float* tsum  = (float*)(ws + O_TSUM);
    float* bleed = (float*)(ws + O_BLEED);
    __shared__ unsigned int smax[NB];
    if (threadIdx.x < NB) smax[threadIdx.x] = 0u;
    __syncthreads();
    int chunk = (n + gridDim.x - 1) / (int)gridDim.x;
    int start = blockIdx.x * chunk;
    int end   = min(start + chunk, n);
    for (int i = start + (int)threadIdx.x; i < end; i += (int)blockDim.x) {
        const float* r = ev + (size_t)5 * (size_t)i;
        int xi = (int)r[0], yi = (int)r[1], bi = (int)r[4];
        float t = r[2];
        atomicMax(&smax[bi], __float_as_uint(t));
        atomicAdd(&cont[xi + NW * yi + CELLS * bi], 1);
        int loc = (xi >> 1) + (NW / 4) * yi;
        int ik  = loc + SEG * bi;
        if (ik < HALF) {
            atomicAdd(&cnt[ik], 1);
            if (loc >= SEG) atomicAdd(&bleed[ik], t);
            else            atomicAdd(&tsum[ik], t);
        }
    }
    __syncthreads();
    if (threadIdx.x < NB) {
        unsigned v = smax[threadIdx.x];
        if (v) atomicMax(&tmaxb[threadIdx.x], v);
    }
}

__global__ __launch_bounds__(256) void f_epilogue(const unsigned int* __restrict__ ws,
                                                  float* __restrict__ out) {
    const unsigned int* tmaxb = ws + O_TMAX;
    const int*   cont  = (const int*)(ws + O_CONT);
    const int*   cnt   = (const int*)(ws + O_CNTFB + 32);
    const float* tsum  = (const float*)(ws + O_TSUM);
    const float* bleed = (const float*)(ws + O_BLEED);
    int v = blockIdx.x * blockDim.x + threadIdx.x;
    if (v >= HALF) return;
    int b   = v / SEG;
    int rem = v - b * SEG;
    int i   = rem / (NW / 2);
    int j   = rem - i * (NW / 2);
    int cbase = b * CELLS + 480 * i + 2 * j;
    int c00 = cont[cbase],      c01 = cont[cbase + 1];
    int c10 = cont[cbase + NW], c11 = cont[cbase + NW + 1];
    out[cbase]          = (float)c00;
    out[cbase + 1]      = (float)c01;
    out[cbase + NW]     = (float)c10;
    out[cbase + NW + 1] = (float)c11;
    int c = cnt[v];
    out[FULL + v] = (float)c;
    float tm  = __uint_as_float(tmaxb[b]);
    if (!(tm > 0.0f)) tm = 1.0f;
    float tmp = (b > 0) ? __uint_as_float(tmaxb[b - 1]) : 1.0f;
    if (!(tmp > 0.0f)) tmp = 1.0f;
    float s   = tsum[v] / tm + bleed[v] / tmp;
    out[FULL + HALF + v] = s / (float)(c == 0 ? 1 : c);
    out[FULL + 2 * HALF + v] = (float)(c00 - c01 + c10 - c11);
    out[FULL + 3 * HALF + v] = (float)(c00 + c01 - c10 - c11);
}

extern "C" void kernel_launch(void* const* d_in, const int* in_sizes, int n_in,
                              void* d_out, int out_size, void* d_ws, size_t ws_size,
                              hipStream_t stream) {
    const float* ev = (const float*)d_in[0];
    int n = in_sizes[0] / 5;
    unsigned int* ws = (unsigned int*)d_ws;
    float* out = (float*)d_out;

    size_t need = (size_t)(O_PRIV + NBLK * (H4W + SEG)) * 4u;  // ~37.3 MB

    if (ws_size >= need && n > 0) {
        unsigned int* h4p = ws + O_PRIV;
        float*        tsp = (float*)(ws + O_PRIV + NBLK * H4W);
        int*          bnd = (int*)(ws + O_BND);
        hipLaunchKernelGGL(k_init, dim3(512), dim3(256), 0, stream, ws, ZERO_WORDS);
        hipLaunchKernelGGL(k_bounds, dim3(1), dim3(64), 0, stream, ev, n, bnd);
        hipLaunchKernelGGL(k_merged, dim3(NBLK), dim3(EVT), 0, stream, ev, bnd, ws, h4p, tsp);
        hipLaunchKernelGGL(k_reduce, dim3(NB * RT), dim3(256), 0, stream, ws, h4p, tsp, out);
    } else {
        hipLaunchKernelGGL(k_init, dim3(512), dim3(256), 0, stream, ws, ZERO_WORDS + 32 + HALF);
        hipLaunchKernelGGL(f_events, dim3(2048), dim3(256), 0, stream, ev, n, ws);
        hipLaunchKernelGGL(f_epilogue, dim3((HALF + 255) / 256), dim3(256), 0, stream, ws, out);
    }
}

// Round 7
// 255.072 us; speedup vs baseline: 15.0824x; 1.0066x over previous
//
#include <hip/hip_runtime.h>
#include <stdint.h>

// B=16, H=180, W=240, N=8M events of 5 floats (x,y,t,p,b), b sorted.
constexpr int NB    = 16;
constexpr int NH    = 180;
constexpr int NW    = 240;
constexpr int FULL  = NB * NH * NW;         // 691200
constexpr int SEG   = (NH / 2) * (NW / 2);  // 10800
constexpr int HALF  = NB * SEG;             // 172800
constexpr int CELLS = NH * NW;              // 43200 full-res cells per batch
constexpr int H4W   = CELLS / 8;            // 5400 words, 4-bit packed counts
constexpr int EVT   = 1024;                 // threads per event block (16 waves; 2 blk/CU = 32 waves/CU)
constexpr int NBPB  = 32;                   // event blocks per batch (batch-aligned)
constexpr int NBLK  = NB * NBPB;            // 512 event blocks
constexpr int RT    = 43;                   // reduce tiles per batch (43*256 >= SEG)
constexpr int TSX   = SEG + 60;             // ts extended: cells 10800..10859 = bleed row

// ---- ws layout (4-byte words) ----
constexpr int O_TMAX  = 0;                  // u32[16] float-bits, atomicMax
constexpr int O_BLEED = 16;                 // f32[HALF] t-sums bled into next batch's segment
constexpr int ZFAST   = O_BLEED + HALF;     // fast path zeroes only this much (~691KB)
constexpr int O_BND   = ZFAST;              // i32[17] batch boundaries
constexpr int O_PRIV  = O_BND + 32;         // h4[NBLK][5400] then ts[NBLK][10800]
// fallback aliases (scratch reused):
constexpr int O_CONT  = O_PRIV;             // u32[FULL]
constexpr int O_TSUMF = O_CONT + FULL;      // f32[HALF]
constexpr int O_CNTFB = O_TSUMF + HALF;     // u32[HALF]
constexpr int ZFALL   = O_CNTFB + HALF;     // fallback zero bound (~4.8MB)

// Zero [0, bound) and (block 0) compute the 17 batch-boundary binary searches.
__global__ __launch_bounds__(256) void k_init(unsigned int* __restrict__ ws, int bound,
                                              const float* __restrict__ ev, int n) {
    int tid = threadIdx.x;
    int i = blockIdx.x * 256 + tid;
    int stride = gridDim.x * 256;
    for (; i < bound; i += stride) ws[i] = 0u;
    if (blockIdx.x == 0 && tid <= NB) {     // bnd[b] = first i with ev[5i+4] >= b
        int lo = 0, hi = n;
        while (lo < hi) {
            int mid = (lo + hi) >> 1;
            float v = ev[(size_t)5 * mid + 4];
            if (v < (float)tid) lo = mid + 1; else hi = mid;
        }
        ((int*)(ws + O_BND))[tid] = lo;
    }
}

// Single event pass, batch-aligned ranges: block k serves batch k/32, slice
// k%32 -> every event is own-batch (R5 lesson: boundary blocks straggled 2.5x).
// 4-bit full-res hist + f32 half-res t-sums in LDS. ts extended to 10860 so
// the bleed cells (y=179, x>=120 floordiv overflow) take the SAME unconditional
// LDS path (R7: removes the per-event branch); written out once per block.
// EVT=1024 -> 32 waves/CU to cover L3 load latency (R6 lesson: 16 waves left
// ~50% latency exposure; k_merged was ~2x its throughput floor).
__global__ __launch_bounds__(EVT) void k_merged(const float* __restrict__ ev,
                                                unsigned int* __restrict__ ws,
                                                unsigned int* __restrict__ h4p,
                                                float* __restrict__ tsp) {
    unsigned int* tmaxb   = ws + O_TMAX;
    float*        bleed_g = (float*)(ws + O_BLEED);
    const int*    bnd     = (const int*)(ws + O_BND);

    __shared__ unsigned int h4[H4W];    // 21.6 KB
    __shared__ float        ts[TSX];    // 43.4 KB
    __shared__ unsigned int bsm;        // block tmax
    int tid = threadIdx.x;
    for (int i = tid; i < H4W; i += EVT) h4[i] = 0u;
    for (int i = tid; i < TSX; i += EVT) ts[i] = 0.0f;
    if (tid == 0) bsm = 0u;

    int b0 = blockIdx.x >> 5;           // this block's batch (exact)
    int r  = blockIdx.x & (NBPB - 1);
    int sb = bnd[b0], eb = bnd[b0 + 1];
    long long len = (long long)(eb - sb);
    int s = sb + (int)(len * r / NBPB);
    int e = sb + (int)(len * (r + 1) / NBPB);
    __syncthreads();

    float tloc = 0.0f;  // t >= 0

    auto proc = [&](float fx, float fy, float t) {
        int xi = (int)fx, yi = (int)fy;
        int cell = xi + NW * yi;
        int loc  = (xi >> 1) + (NW / 4) * yi;   // <= 10859, always in ts[]
        tloc = fmaxf(tloc, t);
        atomicAdd(&h4[cell >> 3], 1u << ((cell & 7) * 4));
        atomicAdd(&ts[loc], t);
    };

    if (s < e) {
        int as_ = min((s + 3) & ~3, e);          // align to 4 for float4 view
        for (int i = s + tid; i < as_; i += EVT) {   // <=3 prologue events
            const float* rr = ev + (size_t)5 * i;
            proc(rr[0], rr[1], rr[2]);
        }
        int ng = (e - as_) >> 2;                 // full groups of 4 events
        const float4* e4 = (const float4*)ev;
        size_t qbase = (size_t)5 * (size_t)(as_ >> 2);
        for (int g = tid; g < ng; g += 2 * EVT) {
            int g2 = g + EVT;
            size_t qb = qbase + (size_t)5 * g;
            float4 q0 = e4[qb], q1 = e4[qb + 1], q2 = e4[qb + 2],
                   q3 = e4[qb + 3], q4 = e4[qb + 4];
            // [x0 y0 t0 p0][b0 x1 y1 t1][p1 b1 x2 y2][t2 p2 b2 x3][y3 t3 p3 b3]
            if (g2 < ng) {
                size_t qc = qbase + (size_t)5 * g2;
                float4 p0 = e4[qc], p1 = e4[qc + 1], p2 = e4[qc + 2],
                       p3 = e4[qc + 3], p4 = e4[qc + 4];
                proc(q0.x, q0.y, q0.z);
                proc(q1.y, q1.z, q1.w);
                proc(q2.z, q2.w, q3.x);
                proc(q3.w, q4.x, q4.y);
                proc(p0.x, p0.y, p0.z);
                proc(p1.y, p1.z, p1.w);
                proc(p2.z, p2.w, p3.x);
                proc(p3.w, p4.x, p4.y);
            } else {
                proc(q0.x, q0.y, q0.z);
                proc(q1.y, q1.z, q1.w);
                proc(q2.z, q2.w, q3.x);
                proc(q3.w, q4.x, q4.y);
            }
        }
        for (int i = as_ + (ng << 2) + tid; i < e; i += EVT) {  // <=3 tail events
            const float* rr = ev + (size_t)5 * i;
            proc(rr[0], rr[1], rr[2]);
        }
    }

    // per-wave tmax -> one LDS atomic per wave -> one global atomic per block
#pragma unroll
    for (int o = 32; o > 0; o >>= 1) tloc = fmaxf(tloc, __shfl_xor(tloc, o));
    if ((tid & 63) == 0) atomicMax(&bsm, __float_as_uint(tloc));
    __syncthreads();

    unsigned int* dh = h4p + (size_t)blockIdx.x * H4W;
    for (int i = tid; i < H4W; i += EVT) dh[i] = h4[i];
    float* dt = tsp + (size_t)blockIdx.x * SEG;
    for (int i = tid; i < SEG; i += EVT) dt[i] = ts[i];
    // bleed cells: batch b0's events that land in batch b0+1's segment.
    // b0==15 -> ik >= HALF -> dropped (matches jax mode="drop").
    if (b0 < NB - 1 && tid < 60) {
        float v = ts[SEG + tid];
        if (v != 0.0f) atomicAdd(&bleed_g[(b0 + 1) * SEG + tid], v);
    }
    if (tid == 0 && bsm) atomicMax(&tmaxb[b0], bsm);  // 32 per address total
}

// Merge the 32 per-batch private hists; derive counter from container; emit
// all 5 outputs. Constant trip count + unroll 16 for load batching.
__global__ __launch_bounds__(256) void k_reduce(const unsigned int* __restrict__ ws,
                                                const unsigned int* __restrict__ h4p,
                                                const float* __restrict__ tsp,
                                                float* __restrict__ out) {
    const unsigned int* tmaxb   = ws + O_TMAX;
    const float*        bleed_g = (const float*)(ws + O_BLEED);

    int tid  = threadIdx.x;
    int b    = blockIdx.x / RT;
    int tile = blockIdx.x - b * RT;

    int rem = tile * 256 + tid;
    if (rem >= SEG) return;
    int v = b * SEG + rem;
    int i = rem / (NW / 2);
    int j = rem - i * (NW / 2);
    int cbl = 480 * i + 2 * j;           // local cell of C[2i][2j]
    int cbg = CELLS * b + cbl;

    unsigned c00 = 0, c01 = 0, c10 = 0, c11 = 0, oc = 0;
    float tsum = 0.0f;

    // counter[b,i,j] = C[b,2i,2j]+C[b,2i,2j+1] + odd-row shifted pair:
    //   j>=60        -> C[b,2i+1,2j-120..]
    //   j<60 && i>=1 -> C[b,2i-1,2j+120..]
    //   j<60 && i==0 -> C[b-1,179,2j+120..] (prev-batch bleed; none for b==0)
    bool prev = false;
    int ocell;
    if (j >= 60)      ocell = cbl + 120;
    else if (i >= 1)  ocell = cbl - 120;
    else { prev = true; ocell = 43080 + 2 * j; }

    int w0i = cbl >> 3, nib = (cbl & 7) * 4;   // cbl even -> pair in one word
    int w1i = w0i + 30;                        // +240 cells = +30 words
    int owi = ocell >> 3, onib = (ocell & 7) * 4;

    int base = b << 5;
#pragma unroll 16
    for (int k = 0; k < NBPB; ++k) {
        const unsigned int* hp = h4p + (size_t)(base + k) * H4W;
        unsigned w0 = hp[w0i], w1 = hp[w1i], wo = hp[owi];
        float tv = tsp[(size_t)(base + k) * SEG + rem];
        c00 += (w0 >> nib) & 15u;  c01 += (w0 >> (nib + 4)) & 15u;
        c10 += (w1 >> nib) & 15u;  c11 += (w1 >> (nib + 4)) & 15u;
        oc  += ((wo >> onib) & 15u) + ((wo >> (onib + 4)) & 15u);
        tsum += tv;
    }
    if (prev) {
        oc = 0;                               // fast-loop oc was for batch b; discard
        if (b >= 1) {
            int pb = (b - 1) << 5;
#pragma unroll 16
            for (int k = 0; k < NBPB; ++k) {
                unsigned wo = h4p[(size_t)(pb + k) * H4W + owi];
                oc += ((wo >> onib) & 15u) + ((wo >> (onib + 4)) & 15u);
            }
        }
    }
    unsigned cnt = c00 + c01 + oc;

    out[cbg]          = (float)c00;
    out[cbg + 1]      = (float)c01;
    out[cbg + NW]     = (float)c10;
    out[cbg + NW + 1] = (float)c11;
    out[FULL + v] = (float)cnt;

    float tm = __uint_as_float(tmaxb[b]);
    if (!(tm > 0.0f)) tm = 1.0f;                       // empty-batch guard
    float tmp = (b > 0) ? __uint_as_float(tmaxb[b - 1]) : 1.0f;
    if (!(tmp > 0.0f)) tmp = 1.0f;
    float s = tsum / tm + bleed_g[v] / tmp;
    out[FULL + HALF + v] = s / (float)(cnt == 0 ? 1u : cnt);

    out[FULL + 2 * HALF + v] = (float)((int)c00 - (int)c01 + (int)c10 - (int)c11);
    out[FULL + 3 * HALF + v] = (float)((int)c00 + (int)c01 - (int)c10 - (int)c11);
}

// ---------------- fallback (global-atomic R1 path; ws too small) ----------------

__global__ __launch_bounds__(256) void f_events(const float* __restrict__ ev, int n,
                                                unsigned int* __restrict__ ws) {
    unsigned int* tmaxb = ws + O_TMAX;
    int*   cont  = (int*)(ws + O_CONT);
    int*   cnt   = (int*)(ws + O_CNTFB);
    float* tsum  = (float*)(ws + O_TSUMF);
    float* bleed = (float*)(ws + O_BLEED);
    __shared__ unsigned int smax[NB];
    if (threadIdx.x < NB) smax[threadIdx.x] = 0u;
    __syncthreads();
    int chunk = (n + gridDim.x - 1) / (int)gridDim.x;
    int start = blockIdx.x * chunk;
    int end   = min(start + chunk, n);
    for (int i = start + (int)threadIdx.x; i < end; i += (int)blockDim.x) {
        const float* r = ev + (size_t)5 * (size_t)i;
        int xi = (int)r[0], yi = (int)r[1], bi = (int)r[4];
        float t = r[2];
        atomicMax(&smax[bi], __float_as_uint(t));
        atomicAdd(&cont[xi + NW * yi + CELLS * bi], 1);
        int loc = (xi >> 1) + (NW / 4) * yi;
        int ik  = loc + SEG * bi;
        if (ik < HALF) {
            atomicAdd(&cnt[ik], 1);
            if (loc >= SEG) atomicAdd(&bleed[ik], t);
            else            atomicAdd(&tsum[ik], t);
        }
    }
    __syncthreads();
    if (threadIdx.x < NB) {
        unsigned v = smax[threadIdx.x];
        if (v) atomicMax(&tmaxb[threadIdx.x], v);
    }
}

__global__ __launch_bounds__(256) void f_epilogue(const unsigned int* __restrict__ ws,
                                                  float* __restrict__ out) {
    const unsigned int* tmaxb = ws + O_TMAX;
    const int*   cont  = (const int*)(ws + O_CONT);
    const int*   cnt   = (const int*)(ws + O_CNTFB);
    const float* tsum  = (const float*)(ws + O_TSUMF);
    const float* bleed = (const float*)(ws + O_BLEED);
    int v = blockIdx.x * blockDim.x + threadIdx.x;
    if (v >= HALF) return;
    int b   = v / SEG;
    int rem = v - b * SEG;
    int i   = rem / (NW / 2);
    int j   = rem - i * (NW / 2);
    int cbase = b * CELLS + 480 * i + 2 * j;
    int c00 = cont[cbase],      c01 = cont[cbase + 1];
    int c10 = cont[cbase + NW], c11 = cont[cbase + NW + 1];
    out[cbase]          = (float)c00;
    out[cbase + 1]      = (float)c01;
    out[cbase + NW]     = (float)c10;
    out[cbase + NW + 1] = (float)c11;
    int c = cnt[v];
    out[FULL + v] = (float)c;
    float tm  = __uint_as_float(tmaxb[b]);
    if (!(tm > 0.0f)) tm = 1.0f;
    float tmp = (b > 0) ? __uint_as_float(tmaxb[b - 1]) : 1.0f;
    if (!(tmp > 0.0f)) tmp = 1.0f;
    float s   = tsum[v] / tm + bleed[v] / tmp;
    out[FULL + HALF + v] = s / (float)(c == 0 ? 1 : c);
    out[FULL + 2 * HALF + v] = (float)(c00 - c01 + c10 - c11);
    out[FULL + 3 * HALF + v] = (float)(c00 + c01 - c10 - c11);
}

extern "C" void kernel_launch(void* const* d_in, const int* in_sizes, int n_in,
                              void* d_out, int out_size, void* d_ws, size_t ws_size,
                              hipStream_t stream) {
    const float* ev = (const float*)d_in[0];
    int n = in_sizes[0] / 5;
    unsigned int* ws = (unsigned int*)d_ws;
    float* out = (float*)d_out;

    size_t need = (size_t)(O_PRIV + NBLK * (H4W + SEG)) * 4u;  // ~33.9 MB

    if (ws_size >= need && n > 0) {
        unsigned int* h4p = ws + O_PRIV;
        float*        tsp = (float*)(ws + O_PRIV + NBLK * H4W);
        hipLaunchKernelGGL(k_init, dim3(64), dim3(256), 0, stream, ws, ZFAST, ev, n);
        hipLaunchKernelGGL(k_merged, dim3(NBLK), dim3(EVT), 0, stream, ev, ws, h4p, tsp);
        hipLaunchKernelGGL(k_reduce, dim3(NB * RT), dim3(256), 0, stream, ws, h4p, tsp, out);
    } else {
        hipLaunchKernelGGL(k_init, dim3(512), dim3(256), 0, stream, ws, ZFALL, ev, n);
        hipLaunchKernelGGL(f_events, dim3(2048), dim3(256), 0, stream, ev, n, ws);
        hipLaunchKernelGGL(f_epilogue, dim3((HALF + 255) / 256), dim3(256), 0, stream, ws, out);
    }
}

// Round 8
// 249.069 us; speedup vs baseline: 15.4459x; 1.0241x over previous
//
#include <hip/hip_runtime.h>
#include <stdint.h>

// B=16, H=180, W=240, N=8M events of 5 floats (x,y,t,p,b), b sorted.
constexpr int NB    = 16;
constexpr int NH    = 180;
constexpr int NW    = 240;
constexpr int FULL  = NB * NH * NW;         // 691200
constexpr int SEG   = (NH / 2) * (NW / 2);  // 10800
constexpr int HALF  = NB * SEG;             // 172800
constexpr int CELLS = NH * NW;              // 43200 full-res cells per batch
constexpr int H4W   = CELLS / 8;            // 5400 words, 4-bit packed counts
constexpr int EVT   = 1024;                 // threads per event block
constexpr int NBPB  = 16;                   // event blocks per batch (R8: halve scratch+merge)
constexpr int NBLK  = NB * NBPB;            // 256 event blocks (1/CU)
constexpr int RT    = 43;                   // reduce tiles per batch (43*256 >= SEG)
constexpr int TSX   = SEG + 60;             // ts extended: cells 10800..10859 = bleed row

// ---- ws layout (4-byte words) ----
constexpr int O_TMAX  = 0;                  // u32[16] float-bits, atomicMax
constexpr int O_BLEED = 16;                 // f32[HALF] t-sums bled into next batch's segment
constexpr int ZFAST   = O_BLEED + HALF;     // fast path zeroes only this much (~691KB)
constexpr int O_BND   = ZFAST;              // i32[17] batch boundaries
constexpr int O_PRIV  = O_BND + 32;         // h4[NBLK][5400] then ts[NBLK][10800]
// fallback aliases (scratch reused):
constexpr int O_CONT  = O_PRIV;             // u32[FULL]
constexpr int O_TSUMF = O_CONT + FULL;      // f32[HALF]
constexpr int O_CNTFB = O_TSUMF + HALF;     // u32[HALF]
constexpr int ZFALL   = O_CNTFB + HALF;     // fallback zero bound (~4.8MB)

// Zero [0, bound) and (block 0) compute the 17 batch-boundary binary searches.
__global__ __launch_bounds__(256) void k_init(unsigned int* __restrict__ ws, int bound,
                                              const float* __restrict__ ev, int n) {
    int tid = threadIdx.x;
    int i = blockIdx.x * 256 + tid;
    int stride = gridDim.x * 256;
    for (; i < bound; i += stride) ws[i] = 0u;
    if (blockIdx.x == 0 && tid <= NB) {     // bnd[b] = first i with ev[5i+4] >= b
        int lo = 0, hi = n;
        while (lo < hi) {
            int mid = (lo + hi) >> 1;
            float v = ev[(size_t)5 * mid + 4];
            if (v < (float)tid) lo = mid + 1; else hi = mid;
        }
        ((int*)(ws + O_BND))[tid] = lo;
    }
}

// Single event pass, batch-aligned ranges: block k serves batch k/16, slice
// k%16 -> every event is own-batch (R5 lesson: boundary blocks straggled 2.5x
// and set the wall clock). 4-bit full-res hist + f32 half-res t-sums in LDS;
// ts extended to 10860 so bleed cells take the same unconditional LDS path.
// LDS zero/dump vectorized as uint4 (R8).
__global__ __launch_bounds__(EVT) void k_merged(const float* __restrict__ ev,
                                                unsigned int* __restrict__ ws,
                                                unsigned int* __restrict__ h4p,
                                                float* __restrict__ tsp) {
    unsigned int* tmaxb   = ws + O_TMAX;
    float*        bleed_g = (float*)(ws + O_BLEED);
    const int*    bnd     = (const int*)(ws + O_BND);

    __shared__ unsigned int h4[H4W];    // 21.6 KB (5400 words, 16B-aligned)
    __shared__ float        ts[TSX];    // 43.4 KB
    __shared__ unsigned int bsm;        // block tmax
    int tid = threadIdx.x;
    {   // vectorized zero: h4 = 1350 uint4, ts first 2700 uint4 + 15-word tail
        uint4 z = {0u, 0u, 0u, 0u};
        uint4* h4v = (uint4*)h4;
        uint4* tsv = (uint4*)ts;
        for (int i = tid; i < H4W / 4; i += EVT) h4v[i] = z;
        for (int i = tid; i < SEG / 4; i += EVT) tsv[i] = z;
        if (tid < TSX - SEG) ts[SEG + tid] = 0.0f;
        if (tid == 0) bsm = 0u;
    }

    int b0 = blockIdx.x / NBPB;         // this block's batch (exact)
    int r  = blockIdx.x - b0 * NBPB;
    int sb = bnd[b0], eb = bnd[b0 + 1];
    long long len = (long long)(eb - sb);
    int s = sb + (int)(len * r / NBPB);
    int e = sb + (int)(len * (r + 1) / NBPB);
    __syncthreads();

    float tloc = 0.0f;  // t >= 0

    auto proc = [&](float fx, float fy, float t) {
        int xi = (int)fx, yi = (int)fy;
        int cell = xi + NW * yi;
        int loc  = (xi >> 1) + (NW / 4) * yi;   // <= 10859, always in ts[]
        tloc = fmaxf(tloc, t);
        atomicAdd(&h4[cell >> 3], 1u << ((cell & 7) * 4));
        atomicAdd(&ts[loc], t);
    };

    if (s < e) {
        int as_ = min((s + 3) & ~3, e);          // align to 4 for float4 view
        for (int i = s + tid; i < as_; i += EVT) {   // <=3 prologue events
            const float* rr = ev + (size_t)5 * i;
            proc(rr[0], rr[1], rr[2]);
        }
        int ng = (e - as_) >> 2;                 // full groups of 4 events
        const float4* e4 = (const float4*)ev;
        size_t qbase = (size_t)5 * (size_t)(as_ >> 2);
        for (int g = tid; g < ng; g += 2 * EVT) {
            int g2 = g + EVT;
            size_t qb = qbase + (size_t)5 * g;
            float4 q0 = e4[qb], q1 = e4[qb + 1], q2 = e4[qb + 2],
                   q3 = e4[qb + 3], q4 = e4[qb + 4];
            // [x0 y0 t0 p0][b0 x1 y1 t1][p1 b1 x2 y2][t2 p2 b2 x3][y3 t3 p3 b3]
            if (g2 < ng) {
                size_t qc = qbase + (size_t)5 * g2;
                float4 p0 = e4[qc], p1 = e4[qc + 1], p2 = e4[qc + 2],
                       p3 = e4[qc + 3], p4 = e4[qc + 4];
                proc(q0.x, q0.y, q0.z);
                proc(q1.y, q1.z, q1.w);
                proc(q2.z, q2.w, q3.x);
                proc(q3.w, q4.x, q4.y);
                proc(p0.x, p0.y, p0.z);
                proc(p1.y, p1.z, p1.w);
                proc(p2.z, p2.w, p3.x);
                proc(p3.w, p4.x, p4.y);
            } else {
                proc(q0.x, q0.y, q0.z);
                proc(q1.y, q1.z, q1.w);
                proc(q2.z, q2.w, q3.x);
                proc(q3.w, q4.x, q4.y);
            }
        }
        for (int i = as_ + (ng << 2) + tid; i < e; i += EVT) {  // <=3 tail events
            const float* rr = ev + (size_t)5 * i;
            proc(rr[0], rr[1], rr[2]);
        }
    }

    // per-wave tmax -> one LDS atomic per wave -> one global atomic per block
#pragma unroll
    for (int o = 32; o > 0; o >>= 1) tloc = fmaxf(tloc, __shfl_xor(tloc, o));
    if ((tid & 63) == 0) atomicMax(&bsm, __float_as_uint(tloc));
    __syncthreads();

    {   // vectorized dump: b128 LDS reads -> dwordx4 global stores
        const uint4* h4v = (const uint4*)h4;
        const uint4* tsv = (const uint4*)ts;
        uint4* dh = (uint4*)(h4p + (size_t)blockIdx.x * H4W);
        uint4* dt = (uint4*)(tsp + (size_t)blockIdx.x * SEG);
        for (int i = tid; i < H4W / 4; i += EVT) dh[i] = h4v[i];
        for (int i = tid; i < SEG / 4; i += EVT) dt[i] = tsv[i];
    }
    // bleed cells: batch b0's events that land in batch b0+1's segment.
    // b0==15 -> dropped (matches jax mode="drop").
    if (b0 < NB - 1 && tid < 60) {
        float v = ts[SEG + tid];
        if (v != 0.0f) atomicAdd(&bleed_g[(b0 + 1) * SEG + tid], v);
    }
    if (tid == 0 && bsm) atomicMax(&tmaxb[b0], bsm);  // 16 per address total
}

// Merge the 16 per-batch private hists; derive counter from container; emit
// all 5 outputs. Constant trip count, fully unrolled for load batching.
__global__ __launch_bounds__(256) void k_reduce(const unsigned int* __restrict__ ws,
                                                const unsigned int* __restrict__ h4p,
                                                const float* __restrict__ tsp,
                                                float* __restrict__ out) {
    const unsigned int* tmaxb   = ws + O_TMAX;
    const float*        bleed_g = (const float*)(ws + O_BLEED);

    int tid  = threadIdx.x;
    int b    = blockIdx.x / RT;
    int tile = blockIdx.x - b * RT;

    int rem = tile * 256 + tid;
    if (rem >= SEG) return;
    int v = b * SEG + rem;
    int i = rem / (NW / 2);
    int j = rem - i * (NW / 2);
    int cbl = 480 * i + 2 * j;           // local cell of C[2i][2j]
    int cbg = CELLS * b + cbl;

    unsigned c00 = 0, c01 = 0, c10 = 0, c11 = 0, oc = 0;
    float tsum = 0.0f;

    // counter[b,i,j] = C[b,2i,2j]+C[b,2i,2j+1] + odd-row shifted pair:
    //   j>=60        -> C[b,2i+1,2j-120..]
    //   j<60 && i>=1 -> C[b,2i-1,2j+120..]
    //   j<60 && i==0 -> C[b-1,179,2j+120..] (prev-batch bleed; none for b==0)
    bool prev = false;
    int ocell;
    if (j >= 60)      ocell = cbl + 120;
    else if (i >= 1)  ocell = cbl - 120;
    else { prev = true; ocell = 43080 + 2 * j; }

    int w0i = cbl >> 3, nib = (cbl & 7) * 4;   // cbl even -> pair in one word
    int w1i = w0i + 30;                        // +240 cells = +30 words
    int owi = ocell >> 3, onib = (ocell & 7) * 4;

    int base = b * NBPB;
#pragma unroll
    for (int k = 0; k < NBPB; ++k) {
        const unsigned int* hp = h4p + (size_t)(base + k) * H4W;
        unsigned w0 = hp[w0i], w1 = hp[w1i], wo = hp[owi];
        float tv = tsp[(size_t)(base + k) * SEG + rem];
        c00 += (w0 >> nib) & 15u;  c01 += (w0 >> (nib + 4)) & 15u;
        c10 += (w1 >> nib) & 15u;  c11 += (w1 >> (nib + 4)) & 15u;
        oc  += ((wo >> onib) & 15u) + ((wo >> (onib + 4)) & 15u);
        tsum += tv;
    }
    if (prev) {
        oc = 0;                               // fast-loop oc was for batch b; discard
        if (b >= 1) {
            int pb = (b - 1) * NBPB;
#pragma unroll
            for (int k = 0; k < NBPB; ++k) {
                unsigned wo = h4p[(size_t)(pb + k) * H4W + owi];
                oc += ((wo >> onib) & 15u) + ((wo >> (onib + 4)) & 15u);
            }
        }
    }
    unsigned cnt = c00 + c01 + oc;

    out[cbg]          = (float)c00;
    out[cbg + 1]      = (float)c01;
    out[cbg + NW]     = (float)c10;
    out[cbg + NW + 1] = (float)c11;
    out[FULL + v] = (float)cnt;

    float tm = __uint_as_float(tmaxb[b]);
    if (!(tm > 0.0f)) tm = 1.0f;                       // empty-batch guard
    float tmp = (b > 0) ? __uint_as_float(tmaxb[b - 1]) : 1.0f;
    if (!(tmp > 0.0f)) tmp = 1.0f;
    float s = tsum / tm + bleed_g[v] / tmp;
    out[FULL + HALF + v] = s / (float)(cnt == 0 ? 1u : cnt);

    out[FULL + 2 * HALF + v] = (float)((int)c00 - (int)c01 + (int)c10 - (int)c11);
    out[FULL + 3 * HALF + v] = (float)((int)c00 + (int)c01 - (int)c10 - (int)c11);
}

// ---------------- fallback (global-atomic R1 path; ws too small) ----------------

__global__ __launch_bounds__(256) void f_events(const float* __restrict__ ev, int n,
                                                unsigned int* __restrict__ ws) {
    unsigned int* tmaxb = ws + O_TMAX;
    int*   cont  = (int*)(ws + O_CONT);
    int*   cnt   = (int*)(ws + O_CNTFB);
    float* tsum  = (float*)(ws + O_TSUMF);
    float* bleed = (float*)(ws + O_BLEED);
    __shared__ unsigned int smax[NB];
    if (threadIdx.x < NB) smax[threadIdx.x] = 0u;
    __syncthreads();
    int chunk = (n + gridDim.x - 1) / (int)gridDim.x;
    int start = blockIdx.x * chunk;
    int end   = min(start + chunk, n);
    for (int i = start + (int)threadIdx.x; i < end; i += (int)blockDim.x) {
        const float* r = ev + (size_t)5 * (size_t)i;
        int xi = (int)r[0], yi = (int)r[1], bi = (int)r[4];
        float t = r[2];
        atomicMax(&smax[bi], __float_as_uint(t));
        atomicAdd(&cont[xi + NW * yi + CELLS * bi], 1);
        int loc = (xi >> 1) + (NW / 4) * yi;
        int ik  = loc + SEG * bi;
        if (ik < HALF) {
            atomicAdd(&cnt[ik], 1);
            if (loc >= SEG) atomicAdd(&bleed[ik], t);
            else            atomicAdd(&tsum[ik], t);
        }
    }
    __syncthreads();
    if (threadIdx.x < NB) {
        unsigned v = smax[threadIdx.x];
        if (v) atomicMax(&tmaxb[threadIdx.x], v);
    }
}

__global__ __launch_bounds__(256) void f_epilogue(const unsigned int* __restrict__ ws,
                                                  float* __restrict__ out) {
    const unsigned int* tmaxb = ws + O_TMAX;
    const int*   cont  = (const int*)(ws + O_CONT);
    const int*   cnt   = (const int*)(ws + O_CNTFB);
    const float* tsum  = (const float*)(ws + O_TSUMF);
    const float* bleed = (const float*)(ws + O_BLEED);
    int v = blockIdx.x * blockDim.x + threadIdx.x;
    if (v >= HALF) return;
    int b   = v / SEG;
    int rem = v - b * SEG;
    int i   = rem / (NW / 2);
    int j   = rem - i * (NW / 2);
    int cbase = b * CELLS + 480 * i + 2 * j;
    int c00 = cont[cbase],      c01 = cont[cbase + 1];
    int c10 = cont[cbase + NW], c11 = cont[cbase + NW + 1];
    out[cbase]          = (float)c00;
    out[cbase + 1]      = (float)c01;
    out[cbase + NW]     = (float)c10;
    out[cbase + NW + 1] = (float)c11;
    int c = cnt[v];
    out[FULL + v] = (float)c;
    float tm  = __uint_as_float(tmaxb[b]);
    if (!(tm > 0.0f)) tm = 1.0f;
    float tmp = (b > 0) ? __uint_as_float(tmaxb[b - 1]) : 1.0f;
    if (!(tmp > 0.0f)) tmp = 1.0f;
    float s   = tsum[v] / tm + bleed[v] / tmp;
    out[FULL + HALF + v] = s / (float)(c == 0 ? 1 : c);
    out[FULL + 2 * HALF + v] = (float)(c00 - c01 + c10 - c11);
    out[FULL + 3 * HALF + v] = (float)(c00 + c01 - c10 - c11);
}

extern "C" void kernel_launch(void* const* d_in, const int* in_sizes, int n_in,
                              void* d_out, int out_size, void* d_ws, size_t ws_size,
                              hipStream_t stream) {
    const float* ev = (const float*)d_in[0];
    int n = in_sizes[0] / 5;
    unsigned int* ws = (unsigned int*)d_ws;
    float* out = (float*)d_out;

    size_t need = (size_t)(O_PRIV + NBLK * (H4W + SEG)) * 4u;  // ~17.3 MB

    if (ws_size >= need && n > 0) {
        unsigned int* h4p = ws + O_PRIV;
        float*        tsp = (float*)(ws + O_PRIV + NBLK * H4W);
        hipLaunchKernelGGL(k_init, dim3(64), dim3(256), 0, stream, ws, ZFAST, ev, n);
        hipLaunchKernelGGL(k_merged, dim3(NBLK), dim3(EVT), 0, stream, ev, ws, h4p, tsp);
        hipLaunchKernelGGL(k_reduce, dim3(NB * RT), dim3(256), 0, stream, ws, h4p, tsp, out);
    } else {
        hipLaunchKernelGGL(k_init, dim3(512), dim3(256), 0, stream, ws, ZFALL, ev, n);
        hipLaunchKernelGGL(f_events, dim3(2048), dim3(256), 0, stream, ev, n, ws);
        hipLaunchKernelGGL(f_epilogue, dim3((HALF + 255) / 256), dim3(256), 0, stream, ws, out);
    }
}

// Round 9
// 244.539 us; speedup vs baseline: 15.7321x; 1.0185x over previous
//
#include <hip/hip_runtime.h>
#include <stdint.h>

// B=16, H=180, W=240, N=8M events of 5 floats (x,y,t,p,b), b sorted.
constexpr int NB    = 16;
constexpr int NH    = 180;
constexpr int NW    = 240;
constexpr int FULL  = NB * NH * NW;         // 691200
constexpr int SEG   = (NH / 2) * (NW / 2);  // 10800
constexpr int HALF  = NB * SEG;             // 172800
constexpr int CELLS = NH * NW;              // 43200 full-res cells per batch
constexpr int H4W   = CELLS / 8;            // 5400 words, 4-bit packed counts
constexpr int EVT   = 1024;                 // threads per event block
constexpr int NBPB  = 16;                   // event blocks per batch (batch-aligned)
constexpr int NBLK  = NB * NBPB;            // 256 event blocks (1/CU)
constexpr int RT    = 43;                   // reduce tiles per batch (43*256 >= SEG)
constexpr int TSX   = SEG + 60;             // ts extended: cells 10800..10859 = bleed row

// ---- fast-path ws layout (4-byte words): NOTHING needs pre-zeroing ----
constexpr int O_TMAXB = 0;                  // f32[NBLK] per-block tmax (plain stores)
constexpr int O_BLDP  = NBLK;               // f32[NBLK][60] per-block bleed stripes
constexpr int O_PRIV  = O_BLDP + NBLK * 60; // h4[NBLK][5400] then ts[NBLK][10800]
// ---- fallback layout (R1-style; needs zeroing) ----
constexpr int FB_TMAX  = 0;                 // u32[16]
constexpr int FB_BLEED = 16;                // f32[HALF]
constexpr int FB_CONT  = FB_BLEED + HALF;   // u32[FULL]
constexpr int FB_TSUM  = FB_CONT + FULL;    // f32[HALF]
constexpr int FB_CNT   = FB_TSUM + HALF;    // u32[HALF]
constexpr int ZFALL    = FB_CNT + HALF;     // ~4.8 MB

// Single event pass, batch-aligned ranges: block k serves batch k/16, slice
// k%16 -> every event is own-batch (R5: boundary blocks straggled 2.5x).
// R9: fully init-free. Lanes 0-1 binary-search this block's [sb,eb) while
// threads >=2 zero the LDS; all outputs are private per-block (plain stores,
// no global atomics, nothing pre-zeroed).
__global__ __launch_bounds__(EVT) void k_merged(const float* __restrict__ ev, int n,
                                                unsigned int* __restrict__ ws,
                                                unsigned int* __restrict__ h4p,
                                                float* __restrict__ tsp) {
    float* tmax_blk = (float*)(ws + O_TMAXB);
    float* bleed_p  = (float*)(ws + O_BLDP);

    __shared__ unsigned int h4[H4W];    // 21.6 KB: 43200 4-bit counters
    __shared__ float        ts[TSX];    // 43.4 KB (incl 60-cell bleed row)
    __shared__ int          sbe[2];
    __shared__ unsigned int bsm;        // block tmax (float bits, t>=0)
    int tid = threadIdx.x;
    int b0 = blockIdx.x / NBPB;         // this block's batch (exact)
    int r  = blockIdx.x - b0 * NBPB;

    if (tid < 2) {                      // bnd search: first i with ev[5i+4] >= b0+tid
        int target = b0 + tid;
        int lo = 0, hi = n;
        while (lo < hi) {
            int mid = (lo + hi) >> 1;
            float v = ev[(size_t)5 * mid + 4];
            if (v < (float)target) lo = mid + 1; else hi = mid;
        }
        sbe[tid] = lo;
    } else {                            // meanwhile: vectorized LDS zero
        uint4 z = {0u, 0u, 0u, 0u};
        uint4* h4v = (uint4*)h4;
        uint4* tsv = (uint4*)ts;
        int t2 = tid - 2;
        for (int i = t2; i < H4W / 4; i += EVT - 2) h4v[i] = z;
        for (int i = t2; i < SEG / 4; i += EVT - 2) tsv[i] = z;
        if (t2 < TSX - SEG) ts[SEG + t2] = 0.0f;
        if (tid == 2) bsm = 0u;
    }
    __syncthreads();

    int sb = sbe[0], eb = sbe[1];
    long long len = (long long)(eb - sb);
    int s = sb + (int)(len * r / NBPB);
    int e = sb + (int)(len * (r + 1) / NBPB);

    float tloc = 0.0f;  // t >= 0

    auto proc = [&](float fx, float fy, float t) {
        int xi = (int)fx, yi = (int)fy;
        int cell = xi + NW * yi;
        int loc  = (xi >> 1) + (NW / 4) * yi;   // <= 10859, always in ts[]
        tloc = fmaxf(tloc, t);
        atomicAdd(&h4[cell >> 3], 1u << ((cell & 7) * 4));
        atomicAdd(&ts[loc], t);
    };

    if (s < e) {
        int as_ = min((s + 3) & ~3, e);          // align to 4 for float4 view
        for (int i = s + tid; i < as_; i += EVT) {   // <=3 prologue events
            const float* rr = ev + (size_t)5 * i;
            proc(rr[0], rr[1], rr[2]);
        }
        int ng = (e - as_) >> 2;                 // full groups of 4 events
        const float4* e4 = (const float4*)ev;
        size_t qbase = (size_t)5 * (size_t)(as_ >> 2);
        for (int g = tid; g < ng; g += 2 * EVT) {
            int g2 = g + EVT;
            size_t qb = qbase + (size_t)5 * g;
            float4 q0 = e4[qb], q1 = e4[qb + 1], q2 = e4[qb + 2],
                   q3 = e4[qb + 3], q4 = e4[qb + 4];
            // [x0 y0 t0 p0][b0 x1 y1 t1][p1 b1 x2 y2][t2 p2 b2 x3][y3 t3 p3 b3]
            if (g2 < ng) {
                size_t qc = qbase + (size_t)5 * g2;
                float4 p0 = e4[qc], p1 = e4[qc + 1], p2 = e4[qc + 2],
                       p3 = e4[qc + 3], p4 = e4[qc + 4];
                proc(q0.x, q0.y, q0.z);
                proc(q1.y, q1.z, q1.w);
                proc(q2.z, q2.w, q3.x);
                proc(q3.w, q4.x, q4.y);
                proc(p0.x, p0.y, p0.z);
                proc(p1.y, p1.z, p1.w);
                proc(p2.z, p2.w, p3.x);
                proc(p3.w, p4.x, p4.y);
            } else {
                proc(q0.x, q0.y, q0.z);
                proc(q1.y, q1.z, q1.w);
                proc(q2.z, q2.w, q3.x);
                proc(q3.w, q4.x, q4.y);
            }
        }
        for (int i = as_ + (ng << 2) + tid; i < e; i += EVT) {  // <=3 tail events
            const float* rr = ev + (size_t)5 * i;
            proc(rr[0], rr[1], rr[2]);
        }
    }

    // per-wave tmax -> one LDS atomic per wave -> one plain store per block
#pragma unroll
    for (int o = 32; o > 0; o >>= 1) tloc = fmaxf(tloc, __shfl_xor(tloc, o));
    if ((tid & 63) == 0) atomicMax(&bsm, __float_as_uint(tloc));
    __syncthreads();

    {   // vectorized dump: b128 LDS reads -> dwordx4 global stores
        const uint4* h4v = (const uint4*)h4;
        const uint4* tsv = (const uint4*)ts;
        uint4* dh = (uint4*)(h4p + (size_t)blockIdx.x * H4W);
        uint4* dt = (uint4*)(tsp + (size_t)blockIdx.x * SEG);
        for (int i = tid; i < H4W / 4; i += EVT) dh[i] = h4v[i];
        for (int i = tid; i < SEG / 4; i += EVT) dt[i] = tsv[i];
    }
    // private bleed stripe (zeros included -> fully initialized, no pre-zero):
    // batch b0's events that floordiv-overflowed into batch b0+1's segment.
    if (tid < 60) bleed_p[blockIdx.x * 60 + tid] = ts[SEG + tid];
    if (tid == 0) tmax_blk[blockIdx.x] = __uint_as_float(bsm);
}

// Merge the 16 per-batch private hists; derive counter from container; reduce
// per-block tmax/bleed privates; emit all 5 outputs.
__global__ __launch_bounds__(256) void k_reduce(const unsigned int* __restrict__ ws,
                                                const unsigned int* __restrict__ h4p,
                                                const float* __restrict__ tsp,
                                                float* __restrict__ out) {
    const float* tmax_blk = (const float*)(ws + O_TMAXB);
    const float* bleed_p  = (const float*)(ws + O_BLDP);

    __shared__ float stm[2];
    int tid  = threadIdx.x;
    int b    = blockIdx.x / RT;
    int tile = blockIdx.x - b * RT;

    if (tid < 32) {                      // tmax for batch b (lanes 0-15) and b-1 (16-31)
        int which = tid >> 4;
        int k = tid & 15;
        int bb = b - which;
        float v = (bb >= 0) ? tmax_blk[bb * NBPB + k] : 0.0f;
#pragma unroll
        for (int o = 8; o > 0; o >>= 1) v = fmaxf(v, __shfl_xor(v, o));
        if (k == 0) stm[which] = v;
    }
    __syncthreads();

    int rem = tile * 256 + tid;
    if (rem >= SEG) return;
    int v = b * SEG + rem;
    int i = rem / (NW / 2);
    int j = rem - i * (NW / 2);
    int cbl = 480 * i + 2 * j;           // local cell of C[2i][2j]
    int cbg = CELLS * b + cbl;

    unsigned c00 = 0, c01 = 0, c10 = 0, c11 = 0, oc = 0;
    float tsum = 0.0f, bl = 0.0f;

    // counter[b,i,j] = C[b,2i,2j]+C[b,2i,2j+1] + odd-row shifted pair:
    //   j>=60        -> C[b,2i+1,2j-120..]
    //   j<60 && i>=1 -> C[b,2i-1,2j+120..]
    //   j<60 && i==0 -> C[b-1,179,2j+120..] (prev-batch bleed; none for b==0)
    bool prev = false;
    int ocell;
    if (j >= 60)      ocell = cbl + 120;
    else if (i >= 1)  ocell = cbl - 120;
    else { prev = true; ocell = 43080 + 2 * j; }

    int w0i = cbl >> 3, nib = (cbl & 7) * 4;   // cbl even -> pair in one word
    int w1i = w0i + 30;                        // +240 cells = +30 words
    int owi = ocell >> 3, onib = (ocell & 7) * 4;

    int base = b * NBPB;
#pragma unroll
    for (int k = 0; k < NBPB; ++k) {
        const unsigned int* hp = h4p + (size_t)(base + k) * H4W;
        unsigned w0 = hp[w0i], w1 = hp[w1i], wo = hp[owi];
        float tv = tsp[(size_t)(base + k) * SEG + rem];
        c00 += (w0 >> nib) & 15u;  c01 += (w0 >> (nib + 4)) & 15u;
        c10 += (w1 >> nib) & 15u;  c11 += (w1 >> (nib + 4)) & 15u;
        oc  += ((wo >> onib) & 15u) + ((wo >> (onib + 4)) & 15u);
        tsum += tv;
    }
    if (prev) {
        oc = 0;                               // fast-loop oc was for batch b; discard
        if (b >= 1) {
            int pb = (b - 1) * NBPB;
#pragma unroll
            for (int k = 0; k < NBPB; ++k) {
                unsigned wo = h4p[(size_t)(pb + k) * H4W + owi];
                oc += ((wo >> onib) & 15u) + ((wo >> (onib + 4)) & 15u);
                bl += bleed_p[(pb + k) * 60 + j];   // j == rem < 60 here
            }
        }
    }
    unsigned cnt = c00 + c01 + oc;

    out[cbg]          = (float)c00;
    out[cbg + 1]      = (float)c01;
    out[cbg + NW]     = (float)c10;
    out[cbg + NW + 1] = (float)c11;
    out[FULL + v] = (float)cnt;

    float tm = stm[0];
    if (!(tm > 0.0f)) tm = 1.0f;                       // empty-batch guard
    float tmp = stm[1];
    if (!(tmp > 0.0f)) tmp = 1.0f;
    float s = tsum / tm + bl / tmp;
    out[FULL + HALF + v] = s / (float)(cnt == 0 ? 1u : cnt);

    out[FULL + 2 * HALF + v] = (float)((int)c00 - (int)c01 + (int)c10 - (int)c11);
    out[FULL + 3 * HALF + v] = (float)((int)c00 + (int)c01 - (int)c10 - (int)c11);
}

// ---------------- fallback (global-atomic R1 path; ws too small) ----------------

__global__ __launch_bounds__(256) void f_init(unsigned int* __restrict__ ws, int bound) {
    int i = blockIdx.x * 256 + threadIdx.x;
    int stride = gridDim.x * 256;
    for (; i < bound; i += stride) ws[i] = 0u;
}

__global__ __launch_bounds__(256) void f_events(const float* __restrict__ ev, int n,
                                                unsigned int* __restrict__ ws) {
    unsigned int* tmaxb = ws + FB_TMAX;
    int*   cont  = (int*)(ws + FB_CONT);
    int*   cnt   = (int*)(ws + FB_CNT);
    float* tsum  = (float*)(ws + FB_TSUM);
    float* bleed = (float*)(ws + FB_BLEED);
    __shared__ unsigned int smax[NB];
    if (threadIdx.x < NB) smax[threadIdx.x] = 0u;
    __syncthreads();
    int chunk = (n + gridDim.x - 1) / (int)gridDim.x;
    int start = blockIdx.x * chunk;
    int end   = min(start + chunk, n);
    for (int i = start + (int)threadIdx.x; i < end; i += (int)blockDim.x) {
        const float* r = ev + (size_t)5 * (size_t)i;
        int xi = (int)r[0], yi = (int)r[1], bi = (int)r[4];
        float t = r[2];
        atomicMax(&smax[bi], __float_as_uint(t));
        atomicAdd(&cont[xi + NW * yi + CELLS * bi], 1);
        int loc = (xi >> 1) + (NW / 4) * yi;
        int ik  = loc + SEG * bi;
        if (ik < HALF) {
            atomicAdd(&cnt[ik], 1);
            if (loc >= SEG) atomicAdd(&bleed[ik], t);
            else            atomicAdd(&tsum[ik], t);
        }
    }
    __syncthreads();
    if (threadIdx.x < NB) {
        unsigned v = smax[threadIdx.x];
        if (v) atomicMax(&tmaxb[threadIdx.x], v);
    }
}

__global__ __launch_bounds__(256) void f_epilogue(const unsigned int* __restrict__ ws,
                                                  float* __restrict__ out) {
    const unsigned int* tmaxb = ws + FB_TMAX;
    const int*   cont  = (const int*)(ws + FB_CONT);
    const int*   cnt   = (const int*)(ws + FB_CNT);
    const float* tsum  = (const float*)(ws + FB_TSUM);
    const float* bleed = (const float*)(ws + FB_BLEED);
    int v = blockIdx.x * blockDim.x + threadIdx.x;
    if (v >= HALF) return;
    int b   = v / SEG;
    int rem = v - b * SEG;
    int i   = rem / (NW / 2);
    int j   = rem - i * (NW / 2);
    int cbase = b * CELLS + 480 * i + 2 * j;
    int c00 = cont[cbase],      c01 = cont[cbase + 1];
    int c10 = cont[cbase + NW], c11 = cont[cbase + NW + 1];
    out[cbase]          = (float)c00;
    out[cbase + 1]      = (float)c01;
    out[cbase + NW]     = (float)c10;
    out[cbase + NW + 1] = (float)c11;
    int c = cnt[v];
    out[FULL + v] = (float)c;
    float tm  = __uint_as_float(tmaxb[b]);
    if (!(tm > 0.0f)) tm = 1.0f;
    float tmp = (b > 0) ? __uint_as_float(tmaxb[b - 1]) : 1.0f;
    if (!(tmp > 0.0f)) tmp = 1.0f;
    float s   = tsum[v] / tm + bleed[v] / tmp;
    out[FULL + HALF + v] = s / (float)(c == 0 ? 1 : c);
    out[FULL + 2 * HALF + v] = (float)(c00 - c01 + c10 - c11);
    out[FULL + 3 * HALF + v] = (float)(c00 + c01 - c10 - c11);
}

extern "C" void kernel_launch(void* const* d_in, const int* in_sizes, int n_in,
                              void* d_out, int out_size, void* d_ws, size_t ws_size,
                              hipStream_t stream) {
    const float* ev = (const float*)d_in[0];
    int n = in_sizes[0] / 5;
    unsigned int* ws = (unsigned int*)d_ws;
    float* out = (float*)d_out;

    size_t need = (size_t)(O_PRIV + NBLK * (H4W + SEG)) * 4u;  // ~16.7 MB

    if (ws_size >= need && n > 0) {
        unsigned int* h4p = ws + O_PRIV;
        float*        tsp = (float*)(ws + O_PRIV + NBLK * H4W);
        hipLaunchKernelGGL(k_merged, dim3(NBLK), dim3(EVT), 0, stream, ev, n, ws, h4p, tsp);
        hipLaunchKernelGGL(k_reduce, dim3(NB * RT), dim3(256), 0, stream, ws, h4p, tsp, out);
    } else {
        hipLaunchKernelGGL(f_init, dim3(512), dim3(256), 0, stream, ws, ZFALL);
        hipLaunchKernelGGL(f_events, dim3(2048), dim3(256), 0, stream, ev, n, ws);
        hipLaunchKernelGGL(f_epilogue, dim3((HALF + 255) / 256), dim3(256), 0, stream, ws, out);
    }
}